// Round 9
// baseline (730.661 us; speedup 1.0000x reference)
//
#include <hip/hip_runtime.h>
#include <math.h>
#include <float.h>

#define XG 192
#define YG 132
#define HW 25344           // 192*132
#define NCLS 6
#define NPROP 500
#define LWIN 441
#define CAP 2048           // candidate cap for top-k sort (after 2-level select)

static __device__ __forceinline__ int imin(int a,int b){return a<b?a:b;}
static __device__ __forceinline__ int imax(int a,int b){return a>b?a:b;}

// async global->LDS, 16B per lane; LDS dest is wave-uniform base + lane*16
__device__ __forceinline__ void gl_lds16(const float* gp, float* lp){
  __builtin_amdgcn_global_load_lds(
      (const __attribute__((address_space(1))) unsigned int*)gp,
      (__attribute__((address_space(3))) unsigned int*)lp,
      16, 0, 0);
}

// ---------------- weight transposes (output-indexed: coalesced writes) + zeroing ----------------
__global__ __launch_bounds__(256) void k_wt(const float* __restrict__ Ws,
                                            const float* __restrict__ Whm,
                                            float* __restrict__ WT,
                                            float* __restrict__ W6,
                                            int* __restrict__ Z){
  int t = blockIdx.x*256 + threadIdx.x;
  if (t < 294912){
    int oc = t & 127, m = t >> 7;
    WT[t] = Ws[(size_t)oc*2304 + m];
  }
  if (t < 6912){
    int c = t & 127, row = t >> 7;      // row = cls*9+tap, 54 rows
    int cls = row / 9, tap = row % 9;
    W6[t] = Whm[(size_t)cls*1152 + c*9 + tap];
  }
  if (t < 65824) Z[t] = 0;
}

// ---------------- conv1 v9: 128 threads, 8px x 8oc per thread (two float4 halves) ----------------
// grid (396, 4): 396 = 3 strips(64 px) * 132 cols(j); blockIdx.y = 64-ch group.
// thread: oct = tid&15 -> oc halves [oct*4, oct*4+4) and [+64); pxs = tid>>4 (8 px).
// 64 acc; each weight b128 feeds 32 FMA; LDS single-buffer 21.8KB (R5: dbuf regressed).
__global__ __launch_bounds__(128, 3) void k_conv1(const float* __restrict__ IN,
                                                  const float* __restrict__ WT,
                                                  float* __restrict__ O0, float* __restrict__ O1,
                                                  float* __restrict__ O2, float* __restrict__ O3){
  const int b  = blockIdx.x;
  const int g  = blockIdx.y;
  const int i0 = (b % 3) * 64;
  const int j  = b / 3;
  const int tid = threadIdx.x;
  const int wv  = tid >> 6;
  const int ocA = (tid & 15) * 4;
  const int ocB = ocA + 64;
  const int pxs = tid >> 4;            // 0..7
  __shared__ float wlds[4608];         // 4cc x 9tap x 128oc
  __shared__ float hlds[816];          // 4cc x 3rows x 68 (padded, 16B-aligned rows)
  float4 accA[8], accB[8];
  #pragma unroll
  for (int px=0;px<8;++px){ accA[px]=make_float4(0,0,0,0); accB[px]=make_float4(0,0,0,0); }
  const int C0g = g*64;
  for (int q=0; q<16; ++q){
    __syncthreads();   // previous chunk fully consumed
    const float* wchunk = WT + (size_t)(C0g + q*4)*1152;
    #pragma unroll
    for (int r9=0; r9<9; ++r9)
      gl_lds16(wchunk + (size_t)(r9*128 + tid)*4, wlds + (size_t)(r9*128 + wv*64)*4);
    for (int e=tid; e<792; e+=128){
      int cc = e/198, rem = e%198, r = rem/66, ii = rem%66;
      int gj = j-1+r, gi = i0-1+ii;
      float v = 0.f;
      if ((unsigned)gj < 132u && (unsigned)gi < 192u)
        v = IN[(size_t)(C0g+q*4+cc)*25344 + gj*192 + gi];
      hlds[cc*204 + r*68 + ii] = v;
    }
    __syncthreads();   // staging visible (drains vmcnt incl. global_load_lds)
    for (int cc=0; cc<4; ++cc){
      const float* hb = hlds + cc*204 + pxs*8;
      const float* wb = wlds + cc*1152;
      float a[3][10];
      #pragma unroll
      for (int r=0;r<3;++r)
        #pragma unroll
        for (int v=0; v<10; ++v) a[r][v] = hb[r*68 + v];
      #pragma unroll
      for (int kh=0;kh<3;++kh){
        #pragma unroll
        for (int kw=0;kw<3;++kw){
          float4 wA = *(const float4*)(wb + (kh*3+kw)*128 + ocA);
          float4 wB = *(const float4*)(wb + (kh*3+kw)*128 + ocB);
          #pragma unroll
          for (int px=0;px<8;++px){
            float act = a[kw][px+kh];
            accA[px].x += act*wA.x; accA[px].y += act*wA.y;
            accA[px].z += act*wA.z; accA[px].w += act*wA.w;
            accB[px].x += act*wB.x; accB[px].y += act*wB.y;
            accB[px].z += act*wB.z; accB[px].w += act*wB.w;
          }
        }
      }
    }
  }
  float* dst = (g==0)?O0:((g==1)?O1:((g==2)?O2:O3));
  #pragma unroll
  for (int px=0;px<8;++px){
    int p = (i0 + pxs*8 + px)*132 + j;
    *(float4*)(dst + (size_t)p*128 + ocA) = accA[px];
    *(float4*)(dst + (size_t)p*128 + ocB) = accB[px];
  }
}

// ---------------- combine 4 k-split partials + bias + relu ----------------
__global__ __launch_bounds__(256) void k_cadd(float* __restrict__ LFF,
                                              const float* __restrict__ P1,
                                              const float* __restrict__ P2,
                                              const float* __restrict__ P3,
                                              const float* __restrict__ bias){
  int t = blockIdx.x*256 + threadIdx.x;   // 3168*256 = 811008 float4s
  float4 a = ((const float4*)LFF)[t];
  float4 b = ((const float4*)P1)[t];
  float4 c = ((const float4*)P2)[t];
  float4 d = ((const float4*)P3)[t];
  float4 bs = ((const float4*)bias)[t & 31];
  float4 r;
  r.x = fmaxf(a.x+b.x+c.x+d.x+bs.x, 0.f);
  r.y = fmaxf(a.y+b.y+c.y+d.y+bs.y, 0.f);
  r.z = fmaxf(a.z+b.z+c.z+d.z+bs.z, 0.f);
  r.w = fmaxf(a.w+b.w+c.w+d.w+bs.w, 0.f);
  ((float4*)LFF)[t] = r;
}

// ---------------- fused (kkvv | conv2) : independent consumers of LFF ----------------
// blocks 0..791: kkvv (32 px each). blocks 792..1187: conv2 (64 px each).
__global__ __launch_bounds__(256) void k_mid(const float* __restrict__ LFF,
                                             const float* __restrict__ W1, const float* __restrict__ b1,
                                             const float* __restrict__ W2, const float* __restrict__ b2,
                                             const float* __restrict__ Wk, const float* __restrict__ bk,
                                             const float* __restrict__ Wv, const float* __restrict__ bv,
                                             float* __restrict__ KK, float* __restrict__ VV,
                                             const float* __restrict__ W6, const float* __restrict__ bhm,
                                             float* __restrict__ HMS){
  __shared__ float smem[8448];
  const int tid = threadIdx.x;
  if (blockIdx.x < 792){
    // ---------- kkvv ----------
    float* hs = smem;            // 128*33
    float* sf = smem + 4224;     // 128*33
    const int p0 = blockIdx.x*32;
    for (int e=tid; e<4096; e+=256){
      int k = e>>5, px = e&31;
      int p = p0+px;
      float bx = (float)(p/132)+0.5f, by = (float)(p%132)+0.5f;
      hs[k*33+px] = fmaxf(bx*W1[k] + by*W1[128+k] + b1[k], 0.f);
    }
    for (int e=tid; e<4096; e+=256){
      int px = e>>7, k = e&127;
      sf[k*33+px] = LFF[(size_t)(p0+px)*128 + k];
    }
    __syncthreads();
    const int pxg = tid & 15, ocg = tid >> 4;   // 16 x 16
    const int px0 = pxg*2, oc0 = ocg*8;
    float accA[2][8];
    #pragma unroll
    for (int r=0;r<2;++r)
      #pragma unroll
      for (int u=0;u<8;++u) accA[r][u]=0.f;
    #pragma unroll 2
    for (int k=0;k<128;++k){
      float a0 = hs[k*33+px0], a1 = hs[k*33+px0+1];
      const float4* w = (const float4*)(W2 + (size_t)k*128 + oc0);
      float4 w0 = w[0], w1 = w[1];
      accA[0][0]+=a0*w0.x; accA[0][1]+=a0*w0.y; accA[0][2]+=a0*w0.z; accA[0][3]+=a0*w0.w;
      accA[0][4]+=a0*w1.x; accA[0][5]+=a0*w1.y; accA[0][6]+=a0*w1.z; accA[0][7]+=a0*w1.w;
      accA[1][0]+=a1*w0.x; accA[1][1]+=a1*w0.y; accA[1][2]+=a1*w0.z; accA[1][3]+=a1*w0.w;
      accA[1][4]+=a1*w1.x; accA[1][5]+=a1*w1.y; accA[1][6]+=a1*w1.z; accA[1][7]+=a1*w1.w;
    }
    __syncthreads();
    #pragma unroll
    for (int u=0;u<8;++u){
      float bb = b2[oc0+u];
      hs[(oc0+u)*33+px0]   = sf[(oc0+u)*33+px0]   + accA[0][u] + bb;
      hs[(oc0+u)*33+px0+1] = sf[(oc0+u)*33+px0+1] + accA[1][u] + bb;
    }
    __syncthreads();
    float accK[2][8], accV[2][8];
    #pragma unroll
    for (int u=0;u<8;++u){
      float k0 = bk[oc0+u], v0 = bv[oc0+u];
      accK[0][u]=k0; accK[1][u]=k0; accV[0][u]=v0; accV[1][u]=v0;
    }
    #pragma unroll 2
    for (int k=0;k<128;++k){
      float s0 = hs[k*33+px0], s1 = hs[k*33+px0+1];
      float f0 = sf[k*33+px0], f1 = sf[k*33+px0+1];
      const float4* wk = (const float4*)(Wk + (size_t)k*128 + oc0);
      const float4* wv = (const float4*)(Wv + (size_t)k*128 + oc0);
      float4 k0v = wk[0], k1v = wk[1], v0v = wv[0], v1v = wv[1];
      accK[0][0]+=s0*k0v.x; accK[0][1]+=s0*k0v.y; accK[0][2]+=s0*k0v.z; accK[0][3]+=s0*k0v.w;
      accK[0][4]+=s0*k1v.x; accK[0][5]+=s0*k1v.y; accK[0][6]+=s0*k1v.z; accK[0][7]+=s0*k1v.w;
      accK[1][0]+=s1*k0v.x; accK[1][1]+=s1*k0v.y; accK[1][2]+=s1*k0v.z; accK[1][3]+=s1*k0v.w;
      accK[1][4]+=s1*k1v.x; accK[1][5]+=s1*k1v.y; accK[1][6]+=s1*k1v.z; accK[1][7]+=s1*k1v.w;
      accV[0][0]+=f0*v0v.x; accV[0][1]+=f0*v0v.y; accV[0][2]+=f0*v0v.z; accV[0][3]+=f0*v0v.w;
      accV[0][4]+=f0*v1v.x; accV[0][5]+=f0*v1v.y; accV[0][6]+=f0*v1v.z; accV[0][7]+=f0*v1v.w;
      accV[1][0]+=f1*v0v.x; accV[1][1]+=f1*v0v.y; accV[1][2]+=f1*v0v.z; accV[1][3]+=f1*v0v.w;
      accV[1][4]+=f1*v1v.x; accV[1][5]+=f1*v1v.y; accV[1][6]+=f1*v1v.z; accV[1][7]+=f1*v1v.w;
    }
    #pragma unroll
    for (int r=0;r<2;++r){
      int p = p0+px0+r;
      float4* oK = (float4*)(KK + (size_t)p*128 + oc0);
      float4* oV = (float4*)(VV + (size_t)p*128 + oc0);
      float4 t0, t1;
      t0.x=accK[r][0]; t0.y=accK[r][1]; t0.z=accK[r][2]; t0.w=accK[r][3];
      t1.x=accK[r][4]; t1.y=accK[r][5]; t1.z=accK[r][6]; t1.w=accK[r][7];
      oK[0]=t0; oK[1]=t1;
      t0.x=accV[r][0]; t0.y=accV[r][1]; t0.z=accV[r][2]; t0.w=accV[r][3];
      t1.x=accV[r][4]; t1.y=accV[r][5]; t1.z=accV[r][6]; t1.w=accV[r][7];
      oV[0]=t0; oV[1]=t1;
    }
  } else {
    // ---------- conv2 (R6-proven structure) ----------
    int lane = tid & 63, wave = tid >> 6;
    int p = (blockIdx.x - 792)*64 + lane;        // 396*64 = 25344
    int i = p/132, j = p%132;
    float acc[6] = {0.f,0.f,0.f,0.f,0.f,0.f};
    int cbase = wave*32;
    #pragma unroll
    for (int kh=0; kh<3; ++kh){
      int gi = i+kh-1;
      if ((unsigned)gi >= 192u) continue;
      #pragma unroll
      for (int kw=0; kw<3; ++kw){
        int gj = j+kw-1;
        if ((unsigned)gj >= 132u) continue;
        const float* row = LFF + (size_t)(gi*132+gj)*128 + cbase;
        int tap = kh*3+kw;
        #pragma unroll
        for (int cq=0; cq<8; ++cq){
          float4 v = *(const float4*)(row + cq*4);
          #pragma unroll
          for (int cls=0; cls<6; ++cls){
            float4 wv = *(const float4*)(W6 + (size_t)(cls*9+tap)*128 + cbase + cq*4);
            acc[cls] += v.x*wv.x + v.y*wv.y + v.z*wv.z + v.w*wv.w;
          }
        }
      }
    }
    float* red = smem;    // [4][6][64]
    #pragma unroll
    for (int c=0;c<6;++c) red[(wave*6+c)*64 + lane] = acc[c];
    __syncthreads();
    if (wave==0){
      #pragma unroll
      for (int c=0;c<6;++c){
        float s = red[c*64+lane] + red[(6+c)*64+lane] + red[(12+c)*64+lane] + red[(18+c)*64+lane] + bhm[c];
        HMS[(size_t)c*HW + p] = 1.f/(1.f+expf(-s));
      }
    }
  }
}

// ---------------- NMS + threshold + 16-bit histogram ----------------
__global__ __launch_bounds__(256) void k_nms(const float* __restrict__ HMS,
                                             float* __restrict__ VALS,
                                             int* __restrict__ HIST){
  int t = blockIdx.x*256 + threadIdx.x;   // 594*256 = 152064
  int c = t / HW, p = t % HW;
  int i = p/132, j = p%132;
  float h = HMS[t];
  float v;
  if (c < 3){
    v = 0.f;
    if (i>=1 && i<=190 && j>=1 && j<=130){
      float m = -1e30f;
      #pragma unroll
      for (int di=-1;di<=1;++di)
        #pragma unroll
        for (int dj=-1;dj<=1;++dj)
          m = fmaxf(m, HMS[(size_t)c*HW + (i+di)*132 + (j+dj)]);
      if (h == m) v = h;
    }
  } else v = h;
  if (!(v > 0.01f)) v = 0.f;
  VALS[t] = v;
  if (v > 0.f) atomicAdd(HIST + (__float_as_uint(v)>>16), 1);
}

// ---------------- level-1 scan v2: parallel suffix scan (was 770-iter serial) ----------------
__global__ __launch_bounds__(1024) void k_scan(const int* __restrict__ HIST, int* __restrict__ SCAN){
  __shared__ int part[1024];
  __shared__ int gsel;
  int t = threadIdx.x;
  int s = 0, base = t*64;
  for (int u=0;u<64;++u) s += HIST[base+u];
  part[t] = s;
  __syncthreads();
  // inclusive suffix scan over the 1024 group sums (Hillis-Steele)
  for (int off=1; off<1024; off<<=1){
    int add = (t+off < 1024) ? part[t+off] : 0;
    __syncthreads();
    part[t] += add;
    __syncthreads();
  }
  int total = part[0];
  int mineI = part[t];
  int nextI = (t < 1023) ? part[t+1] : 0;
  if (mineI >= NPROP && nextI < NPROP) gsel = t;
  if (t == 0 && total < NPROP) gsel = -1;
  __syncthreads();
  int g = gsel;
  if (g < 0){
    if (t==0){ SCAN[0] = 0; SCAN[1] = total; }
    return;
  }
  int cumG = (g < 1023) ? part[g+1] : 0;   // count strictly above group g
  if (t < 64){
    int x = HIST[g*64 + t];
    #pragma unroll
    for (int off=1; off<64; off<<=1){
      int y = __shfl_down(x, off);
      x += (t + off < 64) ? y : 0;
    }
    int Snext = __shfl_down(x, 1);
    int incl  = cumG + x;
    int nextc = (t==63) ? cumG : cumG + Snext;
    if (incl >= NPROP && nextc < NPROP){
      SCAN[0] = g*64 + t;
      SCAN[1] = nextc;
    }
  }
}

// ---------------- level-2 histogram (8 more bits inside bstar bin) ----------------
__global__ __launch_bounds__(256) void k_hist2(const float* __restrict__ VALS,
                                               const int* __restrict__ SCAN,
                                               int* __restrict__ H2){
  int t = blockIdx.x*256 + threadIdx.x;
  float v = VALS[t];
  if (v > 0.f){
    unsigned u = __float_as_uint(v);
    if ((int)(u>>16) == SCAN[0]) atomicAdd(H2 + ((u>>8)&255), 1);
  }
}

// ---------------- collect candidates above (bstar,sstar); sstar computed per-block ----------------
__global__ __launch_bounds__(256) void k_collect(const float* __restrict__ VALS,
                                                 const int* __restrict__ SCAN,
                                                 const int* __restrict__ H2,
                                                 int* __restrict__ CNT,
                                                 float* __restrict__ CV, int* __restrict__ CI){
  __shared__ int h2s[256];
  __shared__ int sstarL;
  int tid = threadIdx.x;
  h2s[tid] = H2[tid];
  __syncthreads();
  if (tid == 0){
    int needed = NPROP - SCAN[1];
    int cum = 0, ss = 0;
    for (int s=255; s>=0; --s){
      cum += h2s[s];
      if (cum >= needed){ ss = s; break; }
    }
    sstarL = ss;
  }
  __syncthreads();
  int t = blockIdx.x*256 + tid;   // 594*256 = 152064
  float v = VALS[t];
  if (v > 0.f){
    unsigned u = __float_as_uint(v);
    int bin = (int)(u>>16), sub = (int)((u>>8)&255);
    int bstar = SCAN[0];
    if (bin > bstar || (bin == bstar && sub >= sstarL)){
      int pos = atomicAdd(CNT, 1);
      if (pos < CAP){ CV[pos] = v; CI[pos] = t; }
    }
  }
}

// ---------------- bitonic sort candidates (2048), take top-500 ----------------
__global__ __launch_bounds__(1024) void k_sort(const float* __restrict__ CV, const int* __restrict__ CI,
                                               const int* __restrict__ CNT,
                                               int* __restrict__ TOPS, int* __restrict__ TOPC){
  __shared__ float sv[CAP];
  __shared__ int   si[CAP];
  int tid = threadIdx.x;
  int M = imin(CNT[0], CAP);
  for (int i=tid; i<CAP; i+=1024){
    if (i < M){ sv[i] = CV[i]; si[i] = CI[i]; }
    else      { sv[i] = -1.f;  si[i] = 0x7fffffff; }
  }
  __syncthreads();
  for (int k=2; k<=CAP; k<<=1){
    for (int j=k>>1; j>0; j>>=1){
      for (int i=tid; i<CAP; i+=1024){
        int p = i ^ j;
        if (p > i){
          bool up = ((i & k) == 0);
          float va = sv[i], vb = sv[p];
          int ia = si[i], ib = si[p];
          bool aFirst = (va > vb) || (va == vb && ia < ib);
          bool bFirst = (vb > va) || (vb == va && ib < ia);
          bool doswap = up ? bFirst : aFirst;
          if (doswap){ sv[i]=vb; sv[p]=va; si[i]=ib; si[p]=ia; }
        }
      }
      __syncthreads();
    }
  }
  for (int t=tid; t<NPROP; t+=1024){
    int idx = imin(si[t], NCLS*HW - 1);
    TOPC[t] = idx / HW;
    TOPS[t] = idx % HW;
  }
}

// ---------------- fused qbuild + attention + LN/FFN/LN + heads + decode (split-k phases) ------
__global__ __launch_bounds__(256) void k_attn(const float* __restrict__ KK, const float* __restrict__ VV,
                                              const float* __restrict__ LFF,
                                              const int* __restrict__ TOPS, const int* __restrict__ TOPC,
                                              const float* __restrict__ Wcls, const float* __restrict__ bcls,
                                              const float* __restrict__ pW1, const float* __restrict__ pb1,
                                              const float* __restrict__ pW2, const float* __restrict__ pb2,
                                              const float* __restrict__ Wq, const float* __restrict__ bq,
                                              const float* __restrict__ Wo, const float* __restrict__ bo,
                                              const float* __restrict__ g1, const float* __restrict__ b1,
                                              const float* __restrict__ Wf1, const float* __restrict__ bf1,
                                              const float* __restrict__ Wf2, const float* __restrict__ bf2,
                                              const float* __restrict__ g2, const float* __restrict__ b2,
                                              const float* __restrict__ Wc, const float* __restrict__ bc,
                                              const float* __restrict__ Wh, const float* __restrict__ bh,
                                              const float* __restrict__ Wd, const float* __restrict__ bd,
                                              const float* __restrict__ Wr, const float* __restrict__ br,
                                              const float* __restrict__ Whm2, const float* __restrict__ bhm2,
                                              float* __restrict__ out){
  int n = blockIdx.x, tid = threadIdx.x;
  __shared__ __align__(16) float qhL[128];
  __shared__ float sc[8*441];                 // scores; also split-k partial scratch
  __shared__ int   kiL[441];
  __shared__ __align__(16) float ctxL[128];   // pos-emb hidden in qbuild phase, then ctx
  __shared__ float xL[128];
  __shared__ float hidL[256];
  __shared__ float sumsL[8];
  __shared__ float stat[2];
  __shared__ float dots[16];
  int sp = TOPS[n];
  int cls = TOPC[n];
  const int kb64 = (tid>>7)*64, c128 = tid&127;
  // ---- qbuild: h = relu(pos@W1+b1); q = lff+Wcls+bcls; qin = q + h@W2+b2; qh = qin@Wq+bq ----
  float qreg = 0.f;
  if (tid < 128){
    float qx = (float)(sp/132)+0.5f, qy = (float)(sp%132)+0.5f;
    ctxL[tid] = fmaxf(qx*pW1[tid] + qy*pW1[128+tid] + pb1[tid], 0.f);
    qreg = LFF[(size_t)sp*128+tid] + Wcls[tid*6+cls] + bcls[tid];
  }
  __syncthreads();
  {
    float pe = 0.f;
    for (int k=kb64; k<kb64+64; ++k) pe += ctxL[k]*pW2[(size_t)k*128+c128];
    sc[tid] = pe;
  }
  __syncthreads();
  if (tid < 128) xL[tid] = qreg + pb2[tid] + sc[tid] + sc[tid+128];
  __syncthreads();
  {
    float qh = 0.f;
    for (int k=kb64; k<kb64+64; ++k) qh += xL[k]*Wq[(size_t)k*128+c128];
    sc[tid] = qh;
  }
  __syncthreads();
  if (tid < 128) qhL[tid] = bq[tid] + sc[tid] + sc[tid+128];
  __syncthreads();
  // ---- scores over 441-key window ----
  int spx = sp/192, spy = sp%132;       // faithful to ref's //X_GRID, %Y_GRID
  for (int l = tid; l < 441; l += 256){
    int a = l/21, bb = l%21;
    int kidx = (spx + a - 10)*192 + (spy + bb - 10);
    bool msk = (kidx < 0) || (kidx >= HW);
    int kc = imin(imax(kidx,0), HW-1);
    kiL[l] = kc;
    const float4* kk4 = (const float4*)(KK + (size_t)kc*128);
    const float4* qh4 = (const float4*)qhL;
    #pragma unroll
    for (int hh=0; hh<8; ++hh){
      float acc = 0.f;
      #pragma unroll
      for (int d4=0; d4<4; ++d4){
        float4 kv = kk4[hh*4+d4]; float4 qv = qh4[hh*4+d4];
        acc += kv.x*qv.x + kv.y*qv.y + kv.z*qv.z + kv.w*qv.w;
      }
      sc[hh*441+l] = msk ? -1e9f : acc*0.25f;
    }
  }
  __syncthreads();
  int wave = tid>>6, lane = tid&63;
  for (int hh = wave; hh < 8; hh += 4){
    float mx = -3.0e38f;
    for (int l = lane; l < 441; l += 64) mx = fmaxf(mx, sc[hh*441+l]);
    #pragma unroll
    for (int off=32; off; off>>=1) mx = fmaxf(mx, __shfl_xor(mx, off));
    float sum = 0.f;
    for (int l = lane; l < 441; l += 64){
      float e = __expf(sc[hh*441+l] - mx);
      sc[hh*441+l] = e; sum += e;
    }
    #pragma unroll
    for (int off=32; off; off>>=1) sum += __shfl_xor(sum, off);
    if (lane==0) sumsL[hh] = sum;
  }
  __syncthreads();
  for (int hh = wave; hh < 8; hh += 4){
    float a[16];
    #pragma unroll
    for (int d=0; d<16; ++d) a[d]=0.f;
    for (int l = lane; l < 441; l += 64){
      float w = sc[hh*441+l];
      const float4* vv4 = (const float4*)(VV + (size_t)kiL[l]*128 + hh*16);
      #pragma unroll
      for (int d4=0; d4<4; ++d4){
        float4 v = vv4[d4];
        a[d4*4+0]+=w*v.x; a[d4*4+1]+=w*v.y; a[d4*4+2]+=w*v.z; a[d4*4+3]+=w*v.w;
      }
    }
    #pragma unroll
    for (int d=0; d<16; ++d){
      #pragma unroll
      for (int off=32; off; off>>=1) a[d] += __shfl_xor(a[d], off);
    }
    if (lane==0){
      float inv = 1.f/sumsL[hh];
      #pragma unroll
      for (int d=0; d<16; ++d) ctxL[hh*16+d] = a[d]*inv;
    }
  }
  __syncthreads();
  // ---- x1 = q + ctx@Wo + bo (split-k) ----
  {
    float acc = 0.f;
    for (int k=kb64; k<kb64+64; ++k) acc += ctxL[k]*Wo[(size_t)k*128+c128];
    sc[tid] = acc;
  }
  __syncthreads();
  float x1v = 0.f;
  if (tid < 128){
    x1v = qreg + bo[tid] + sc[tid] + sc[tid+128];
    xL[tid] = x1v;
  }
  __syncthreads();
  if (tid < 64){
    float u0 = xL[tid], u1 = xL[tid+64];
    float s = u0+u1, s2 = u0*u0+u1*u1;
    #pragma unroll
    for (int off=32; off; off>>=1){ s += __shfl_xor(s, off); s2 += __shfl_xor(s2, off); }
    if (tid==0){ float mean = s*(1.f/128.f); float var = s2*(1.f/128.f) - mean*mean;
      stat[0]=mean; stat[1]=rsqrtf(var + 1e-5f); }
  }
  __syncthreads();
  if (tid < 128) xL[tid] = (x1v - stat[0])*stat[1]*g1[tid] + b1[tid];
  __syncthreads();
  {
    float hv = bf1[tid];
    for (int k=0;k<128;++k) hv += xL[k]*Wf1[(size_t)k*256+tid];
    hidL[tid] = fmaxf(hv, 0.f);
  }
  __syncthreads();
  // ---- x2 = x1ln + hid@Wf2 + bf2 (split-k over 256) ----
  {
    int kb = (tid>>7)*128;
    float acc = 0.f;
    for (int k=kb; k<kb+128; ++k) acc += hidL[k]*Wf2[(size_t)k*128+c128];
    sc[tid] = acc;
  }
  __syncthreads();
  float x2v = 0.f;
  if (tid < 128) x2v = xL[tid] + bf2[tid] + sc[tid] + sc[tid+128];
  __syncthreads();
  if (tid < 128) hidL[tid] = x2v;
  __syncthreads();
  if (tid < 64){
    float u0 = hidL[tid], u1 = hidL[tid+64];
    float s = u0+u1, s2 = u0*u0+u1*u1;
    #pragma unroll
    for (int off=32; off; off>>=1){ s += __shfl_xor(s, off); s2 += __shfl_xor(s2, off); }
    if (tid==0){ float mean = s*(1.f/128.f); float var = s2*(1.f/128.f) - mean*mean;
      stat[0]=mean; stat[1]=rsqrtf(var + 1e-5f); }
  }
  __syncthreads();
  if (tid < 128) xL[tid] = (x2v - stat[0])*stat[1]*g2[tid] + b2[tid];   // final x2
  __syncthreads();
  // ---- prediction heads (14 dots) + box decode ----
  if (tid < 14){
    const float* Wp; float bb;
    if (tid < 2)      { Wp = Wc + tid*128;        bb = bc[tid];      }
    else if (tid < 3) { Wp = Wh;                  bb = bh[0];        }
    else if (tid < 6) { Wp = Wd + (tid-3)*128;    bb = bd[tid-3];    }
    else if (tid < 8) { Wp = Wr + (tid-6)*128;    bb = br[tid-6];    }
    else              { Wp = Whm2 + (tid-8)*128;  bb = bhm2[tid-8];  }
    float acc = bb;
    for (int k=0;k<128;++k) acc += xL[k]*Wp[k];
    dots[tid] = acc;
  }
  __syncthreads();
  if (tid == 0){
    float qpx = (float)(sp/132)+0.5f, qpy = (float)(sp%132)+0.5f;
    float cx = (dots[0]+qpx)*0.64f - 61.44f;
    float cy = (dots[1]+qpy)*0.64f - 42.24f;
    float e0 = expf(dots[3]), e1 = expf(dots[4]), e2 = expf(dots[5]);
    float hgt = dots[2] - e2*0.5f;
    float rot = atanf(dots[6]/(dots[7] + 1e-6f));
    float bestv = -1.f; int bestc = 0;
    #pragma unroll
    for (int m=0;m<6;++m){
      float s = 1.f/(1.f + expf(-dots[8+m]));
      if (s > bestv){ bestv = s; bestc = m; }
    }
    float* o = out + (size_t)n*9;
    o[0]=cx; o[1]=cy; o[2]=hgt; o[3]=e0; o[4]=e1; o[5]=e2; o[6]=rot;
    o[7]=(float)bestc; o[8]=bestv;
  }
}

// ---------------- launcher ----------------
extern "C" void kernel_launch(void* const* d_in, const int* in_sizes, int n_in,
                              void* d_out, int out_size, void* d_ws, size_t ws_size,
                              hipStream_t stream){
  (void)in_sizes; (void)n_in; (void)out_size;
  const float* IN   = (const float*)d_in[0];
  const float* Wsh  = (const float*)d_in[1];
  const float* bsh  = (const float*)d_in[2];
  const float* Whm  = (const float*)d_in[3];
  const float* bhm  = (const float*)d_in[4];
  const float* Wcls = (const float*)d_in[5];
  const float* bcls = (const float*)d_in[6];
  const float* Wp1  = (const float*)d_in[7];
  const float* bp1  = (const float*)d_in[8];
  const float* Wp2  = (const float*)d_in[9];
  const float* bp2  = (const float*)d_in[10];
  const float* Wq   = (const float*)d_in[11];
  const float* bq   = (const float*)d_in[12];
  const float* Wk   = (const float*)d_in[13];
  const float* bk   = (const float*)d_in[14];
  const float* Wv   = (const float*)d_in[15];
  const float* bv   = (const float*)d_in[16];
  const float* Wo   = (const float*)d_in[17];
  const float* bo   = (const float*)d_in[18];
  const float* g1   = (const float*)d_in[19];
  const float* b1   = (const float*)d_in[20];
  const float* g2   = (const float*)d_in[21];
  const float* b2   = (const float*)d_in[22];
  const float* Wf1  = (const float*)d_in[23];
  const float* bf1  = (const float*)d_in[24];
  const float* Wf2  = (const float*)d_in[25];
  const float* bf2  = (const float*)d_in[26];
  const float* Wc   = (const float*)d_in[27];
  const float* bc   = (const float*)d_in[28];
  const float* Wh   = (const float*)d_in[29];
  const float* bh   = (const float*)d_in[30];
  const float* Wd   = (const float*)d_in[31];
  const float* bd   = (const float*)d_in[32];
  const float* Wr   = (const float*)d_in[33];
  const float* br   = (const float*)d_in[34];
  const float* Whm2 = (const float*)d_in[37];
  const float* bhm2 = (const float*)d_in[38];
  float* out = (float*)d_out;
  float* W = (float*)d_ws;

  const size_t N_LFF  = (size_t)HW*128;
  const size_t OFF_LFF  = 0;
  const size_t OFF_PE   = OFF_LFF + N_LFF;         // conv1 partial g1
  const size_t OFF_KK   = OFF_PE + N_LFF;          // conv1 partial g2, then KK
  const size_t OFF_VV   = OFF_KK + N_LFF;          // conv1 partial g3, then VV
  const size_t OFF_WT   = OFF_VV + N_LFF;          // 294912
  const size_t OFF_WHMT = OFF_WT + 294912;         // 6912
  const size_t OFF_HMS  = OFF_WHMT + 6912;         // 152064
  const size_t OFF_VALS = OFF_HMS + 152064;        // 152064
  const size_t OFF_HIST = OFF_VALS + 152064;       // 65536
  const size_t OFF_SCAN = OFF_HIST + 65536;        // 16
  const size_t OFF_CNT  = OFF_SCAN + 16;           // 16
  const size_t OFF_H2   = OFF_CNT + 16;            // 256
  const size_t OFF_CV   = OFF_H2 + 256;            // CAP
  const size_t OFF_CI   = OFF_CV + CAP;            // CAP
  const size_t OFF_TOPS = OFF_CI + CAP;            // 512
  const size_t OFF_TOPC = OFF_TOPS + 512;          // 512
  const size_t TOTAL    = OFF_TOPC + 512;
  if (ws_size < TOTAL*sizeof(float)) return;

  // k_wt also zeroes HIST|SCAN|CNT|H2 (65824 ints, contiguous at OFF_HIST)
  k_wt    <<<1152, 256, 0, stream>>>(Wsh, Whm, W+OFF_WT, W+OFF_WHMT, (int*)(W+OFF_HIST));
  k_conv1 <<<dim3(396,4), 128, 0, stream>>>(IN, W+OFF_WT, W+OFF_LFF, W+OFF_PE, W+OFF_KK, W+OFF_VV);
  k_cadd  <<<3168, 256, 0, stream>>>(W+OFF_LFF, W+OFF_PE, W+OFF_KK, W+OFF_VV, bsh);
  k_mid   <<<1188, 256, 0, stream>>>(W+OFF_LFF, Wp1, bp1, Wp2, bp2, Wk, bk, Wv, bv,
                                     W+OFF_KK, W+OFF_VV, W+OFF_WHMT, bhm, W+OFF_HMS);
  k_nms   <<<594,  256, 0, stream>>>(W+OFF_HMS, W+OFF_VALS, (int*)(W+OFF_HIST));
  k_scan  <<<1,   1024, 0, stream>>>((const int*)(W+OFF_HIST), (int*)(W+OFF_SCAN));
  k_hist2 <<<594,  256, 0, stream>>>(W+OFF_VALS, (const int*)(W+OFF_SCAN), (int*)(W+OFF_H2));
  k_collect<<<594, 256, 0, stream>>>(W+OFF_VALS, (const int*)(W+OFF_SCAN), (const int*)(W+OFF_H2),
                                     (int*)(W+OFF_CNT), W+OFF_CV, (int*)(W+OFF_CI));
  k_sort  <<<1,   1024, 0, stream>>>(W+OFF_CV, (const int*)(W+OFF_CI), (const int*)(W+OFF_CNT),
                                     (int*)(W+OFF_TOPS), (int*)(W+OFF_TOPC));
  k_attn  <<<500,  256, 0, stream>>>(W+OFF_KK, W+OFF_VV, W+OFF_LFF,
                                     (const int*)(W+OFF_TOPS), (const int*)(W+OFF_TOPC),
                                     Wcls, bcls, Wp1, bp1, Wp2, bp2, Wq, bq,
                                     Wo, bo, g1, b1, Wf1, bf1, Wf2, bf2, g2, b2,
                                     Wc, bc, Wh, bh, Wd, bd, Wr, br, Whm2, bhm2, out);
}

// Round 10
// 659.256 us; speedup vs baseline: 1.1083x; 1.1083x over previous
//
#include <hip/hip_runtime.h>
#include <math.h>
#include <float.h>

#define XG 192
#define YG 132
#define HW 25344           // 192*132
#define NCLS 6
#define NPROP 500
#define LWIN 441
#define CAP 2048           // candidate cap for top-k sort (one-level select)

static __device__ __forceinline__ int imin(int a,int b){return a<b?a:b;}
static __device__ __forceinline__ int imax(int a,int b){return a>b?a:b;}

// async global->LDS, 16B per lane; LDS dest is wave-uniform base + lane*16
__device__ __forceinline__ void gl_lds16(const float* gp, float* lp){
  __builtin_amdgcn_global_load_lds(
      (const __attribute__((address_space(1))) unsigned int*)gp,
      (__attribute__((address_space(3))) unsigned int*)lp,
      16, 0, 0);
}

// ---------------- weight transposes (output-indexed: coalesced writes) + zeroing ----------------
__global__ __launch_bounds__(256) void k_wt(const float* __restrict__ Ws,
                                            const float* __restrict__ Whm,
                                            float* __restrict__ WT,
                                            float* __restrict__ W6,
                                            int* __restrict__ Z){
  int t = blockIdx.x*256 + threadIdx.x;
  if (t < 294912){
    int oc = t & 127, m = t >> 7;
    WT[t] = Ws[(size_t)oc*2304 + m];
  }
  if (t < 6912){
    int c = t & 127, row = t >> 7;      // row = cls*9+tap, 54 rows
    int cls = row / 9, tap = row % 9;
    W6[t] = Whm[(size_t)cls*1152 + c*9 + tap];
  }
  if (t < 65568) Z[t] = 0;              // HIST 65536 | SCAN 16 | CNT 16
}

// ---------------- conv1 v8 (R8-proven 219us): store-coalesced, 256 threads ----------------
// grid (396, 4): 396 = 3 strips(64 px along i) * 132 cols(j); blockIdx.y = 64-ch group
// thread: oc0 = (tid&31)*4, pxs = tid>>5 (8 px). Tile: 8px x 4oc (32 acc).
// LDS 21.5KB single-buffer (R5: dbuf kills occupancy; R9: 128-thr blocks regressed).
__global__ __launch_bounds__(256, 4) void k_conv1(const float* __restrict__ IN,
                                                  const float* __restrict__ WT,
                                                  float* __restrict__ O0, float* __restrict__ O1,
                                                  float* __restrict__ O2, float* __restrict__ O3){
  const int b  = blockIdx.x;
  const int g  = blockIdx.y;
  const int i0 = (b % 3) * 64;
  const int j  = b / 3;
  const int tid = threadIdx.x;
  const int wv  = tid >> 6;
  const int oc0 = (tid & 31) * 4;
  const int pxs = tid >> 5;            // 0..7
  __shared__ float wlds[4608];         // 4cc x 9tap x 128oc
  __shared__ float hlds[816];          // 4cc x 3rows x 68 (padded, 16B-aligned rows)
  float4 acc[8];
  #pragma unroll
  for (int px=0;px<8;++px) acc[px] = make_float4(0.f,0.f,0.f,0.f);
  const int C0g = g*64;
  for (int q=0; q<16; ++q){
    __syncthreads();   // previous chunk fully consumed
    const float* wchunk = WT + (size_t)(C0g + q*4)*1152;
    #pragma unroll
    for (int r=0; r<4; ++r)
      gl_lds16(wchunk + (size_t)(r*256 + tid)*4, wlds + (size_t)(r*256 + wv*64)*4);
    if (wv < 2)
      gl_lds16(wchunk + (size_t)(1024 + tid)*4, wlds + (size_t)(1024 + wv*64)*4);
    for (int e=tid; e<792; e+=256){
      int cc = e/198, rem = e%198, r = rem/66, ii = rem%66;
      int gj = j-1+r, gi = i0-1+ii;
      float v = 0.f;
      if ((unsigned)gj < 132u && (unsigned)gi < 192u)
        v = IN[(size_t)(C0g+q*4+cc)*25344 + gj*192 + gi];
      hlds[cc*204 + r*68 + ii] = v;
    }
    __syncthreads();   // staging visible (drains vmcnt incl. global_load_lds)
    for (int cc=0; cc<4; ++cc){
      const float* hb = hlds + cc*204 + pxs*8;
      const float* wb = wlds + cc*1152 + oc0;
      float a[3][10];
      #pragma unroll
      for (int r=0;r<3;++r)
        #pragma unroll
        for (int v=0; v<10; ++v) a[r][v] = hb[r*68 + v];
      #pragma unroll
      for (int kh=0;kh<3;++kh){
        #pragma unroll
        for (int kw=0;kw<3;++kw){
          float4 w = *(const float4*)(wb + (kh*3+kw)*128);
          #pragma unroll
          for (int px=0;px<8;++px){
            float act = a[kw][px+kh];
            acc[px].x += act*w.x;
            acc[px].y += act*w.y;
            acc[px].z += act*w.z;
            acc[px].w += act*w.w;
          }
        }
      }
    }
  }
  float* dst = (g==0)?O0:((g==1)?O1:((g==2)?O2:O3));
  #pragma unroll
  for (int px=0;px<8;++px){
    int p = (i0 + pxs*8 + px)*132 + j;
    *(float4*)(dst + (size_t)p*128 + oc0) = acc[px];
  }
}

// ---------------- combine 4 k-split partials + bias + relu ----------------
__global__ __launch_bounds__(256) void k_cadd(float* __restrict__ LFF,
                                              const float* __restrict__ P1,
                                              const float* __restrict__ P2,
                                              const float* __restrict__ P3,
                                              const float* __restrict__ bias){
  int t = blockIdx.x*256 + threadIdx.x;   // 3168*256 = 811008 float4s
  float4 a = ((const float4*)LFF)[t];
  float4 b = ((const float4*)P1)[t];
  float4 c = ((const float4*)P2)[t];
  float4 d = ((const float4*)P3)[t];
  float4 bs = ((const float4*)bias)[t & 31];
  float4 r;
  r.x = fmaxf(a.x+b.x+c.x+d.x+bs.x, 0.f);
  r.y = fmaxf(a.y+b.y+c.y+d.y+bs.y, 0.f);
  r.z = fmaxf(a.z+b.z+c.z+d.z+bs.z, 0.f);
  r.w = fmaxf(a.w+b.w+c.w+d.w+bs.w, 0.f);
  ((float4*)LFF)[t] = r;
}

// ---------------- fused (kkvv | conv2) ; kkvv weights now LDS-staged (R3/R4 lesson) ----------------
// blocks 0..791: kkvv (32 px each). blocks 792..1187: conv2 (64 px each).
__global__ __launch_bounds__(256) void k_mid(const float* __restrict__ LFF,
                                             const float* __restrict__ W1, const float* __restrict__ b1,
                                             const float* __restrict__ W2, const float* __restrict__ b2,
                                             const float* __restrict__ Wk, const float* __restrict__ bk,
                                             const float* __restrict__ Wv, const float* __restrict__ bv,
                                             float* __restrict__ KK, float* __restrict__ VV,
                                             const float* __restrict__ W6, const float* __restrict__ bhm,
                                             float* __restrict__ HMS){
  __shared__ float smem[12288];   // kkvv: hs 4096 | sf 4096 | wbuf 4096 (48KB total)
  const int tid = threadIdx.x;
  const int wv4 = tid >> 6;
  if (blockIdx.x < 792){
    // ---------- kkvv ----------
    float* hs   = smem;            // h in pass A, ss in pass B  [k][px] stride 32
    float* sf   = smem + 4096;     // lff                        [k][px] stride 32
    float* wbuf = smem + 8192;     // staged weight chunk
    const int p0 = blockIdx.x*32;
    for (int e=tid; e<4096; e+=256){
      int k = e>>5, px = e&31;
      int p = p0+px;
      float bx = (float)(p/132)+0.5f, by = (float)(p%132)+0.5f;
      hs[k*32+px] = fmaxf(bx*W1[k] + by*W1[128+k] + b1[k], 0.f);
    }
    for (int e=tid; e<4096; e+=256){
      int px = e>>7, k = e&127;
      sf[k*32+px] = LFF[(size_t)(p0+px)*128 + k];
    }
    const int pxg = tid & 15, ocg = tid >> 4;   // 16 x 16
    const int px0 = pxg*2, oc0 = ocg*8;
    // pass A: pe = h @ W2 (W2 staged in 32-k chunks)
    float accA[2][8];
    #pragma unroll
    for (int r=0;r<2;++r)
      #pragma unroll
      for (int u=0;u<8;++u) accA[r][u]=0.f;
    for (int c0=0; c0<128; c0+=32){
      __syncthreads();
      const float* wsrc = W2 + (size_t)c0*128;
      #pragma unroll
      for (int r=0;r<4;++r)
        gl_lds16(wsrc + (size_t)(r*256+tid)*4, wbuf + (size_t)(r*256+wv4*64)*4);
      __syncthreads();
      #pragma unroll 2
      for (int k=0;k<32;++k){
        float a0 = hs[(c0+k)*32+px0], a1 = hs[(c0+k)*32+px0+1];
        const float4* w = (const float4*)(wbuf + (size_t)k*128 + oc0);
        float4 w0 = w[0], w1 = w[1];
        accA[0][0]+=a0*w0.x; accA[0][1]+=a0*w0.y; accA[0][2]+=a0*w0.z; accA[0][3]+=a0*w0.w;
        accA[0][4]+=a0*w1.x; accA[0][5]+=a0*w1.y; accA[0][6]+=a0*w1.z; accA[0][7]+=a0*w1.w;
        accA[1][0]+=a1*w0.x; accA[1][1]+=a1*w0.y; accA[1][2]+=a1*w0.z; accA[1][3]+=a1*w0.w;
        accA[1][4]+=a1*w1.x; accA[1][5]+=a1*w1.y; accA[1][6]+=a1*w1.z; accA[1][7]+=a1*w1.w;
      }
    }
    __syncthreads();   // all hs reads done
    #pragma unroll
    for (int u=0;u<8;++u){
      float bb = b2[oc0+u];
      hs[(oc0+u)*32+px0]   = sf[(oc0+u)*32+px0]   + accA[0][u] + bb;
      hs[(oc0+u)*32+px0+1] = sf[(oc0+u)*32+px0+1] + accA[1][u] + bb;
    }
    // pass B: KK = ss@Wk+bk, VV = sf@Wv+bv (Wk/Wv staged in 16-k chunks)
    float accK[2][8], accV[2][8];
    #pragma unroll
    for (int u=0;u<8;++u){
      float k0 = bk[oc0+u], v0 = bv[oc0+u];
      accK[0][u]=k0; accK[1][u]=k0; accV[0][u]=v0; accV[1][u]=v0;
    }
    for (int c0=0; c0<128; c0+=16){
      __syncthreads();   // ss writes (first iter) / prev chunk reads done
      #pragma unroll
      for (int r=0;r<2;++r){
        gl_lds16(Wk + (size_t)c0*128 + (size_t)(r*256+tid)*4, wbuf + (size_t)(r*256+wv4*64)*4);
        gl_lds16(Wv + (size_t)c0*128 + (size_t)(r*256+tid)*4, wbuf + 2048 + (size_t)(r*256+wv4*64)*4);
      }
      __syncthreads();
      #pragma unroll 2
      for (int k=0;k<16;++k){
        int kk = c0+k;
        float s0 = hs[kk*32+px0], s1 = hs[kk*32+px0+1];
        float f0 = sf[kk*32+px0], f1 = sf[kk*32+px0+1];
        const float4* wkp = (const float4*)(wbuf + (size_t)k*128 + oc0);
        const float4* wvp = (const float4*)(wbuf + 2048 + (size_t)k*128 + oc0);
        float4 k0v = wkp[0], k1v = wkp[1], v0v = wvp[0], v1v = wvp[1];
        accK[0][0]+=s0*k0v.x; accK[0][1]+=s0*k0v.y; accK[0][2]+=s0*k0v.z; accK[0][3]+=s0*k0v.w;
        accK[0][4]+=s0*k1v.x; accK[0][5]+=s0*k1v.y; accK[0][6]+=s0*k1v.z; accK[0][7]+=s0*k1v.w;
        accK[1][0]+=s1*k0v.x; accK[1][1]+=s1*k0v.y; accK[1][2]+=s1*k0v.z; accK[1][3]+=s1*k0v.w;
        accK[1][4]+=s1*k1v.x; accK[1][5]+=s1*k1v.y; accK[1][6]+=s1*k1v.z; accK[1][7]+=s1*k1v.w;
        accV[0][0]+=f0*v0v.x; accV[0][1]+=f0*v0v.y; accV[0][2]+=f0*v0v.z; accV[0][3]+=f0*v0v.w;
        accV[0][4]+=f0*v1v.x; accV[0][5]+=f0*v1v.y; accV[0][6]+=f0*v1v.z; accV[0][7]+=f0*v1v.w;
        accV[1][0]+=f1*v0v.x; accV[1][1]+=f1*v0v.y; accV[1][2]+=f1*v0v.z; accV[1][3]+=f1*v0v.w;
        accV[1][4]+=f1*v1v.x; accV[1][5]+=f1*v1v.y; accV[1][6]+=f1*v1v.z; accV[1][7]+=f1*v1v.w;
      }
    }
    #pragma unroll
    for (int r=0;r<2;++r){
      int p = p0+px0+r;
      float4* oK = (float4*)(KK + (size_t)p*128 + oc0);
      float4* oV = (float4*)(VV + (size_t)p*128 + oc0);
      float4 t0, t1;
      t0.x=accK[r][0]; t0.y=accK[r][1]; t0.z=accK[r][2]; t0.w=accK[r][3];
      t1.x=accK[r][4]; t1.y=accK[r][5]; t1.z=accK[r][6]; t1.w=accK[r][7];
      oK[0]=t0; oK[1]=t1;
      t0.x=accV[r][0]; t0.y=accV[r][1]; t0.z=accV[r][2]; t0.w=accV[r][3];
      t1.x=accV[r][4]; t1.y=accV[r][5]; t1.z=accV[r][6]; t1.w=accV[r][7];
      oV[0]=t0; oV[1]=t1;
    }
  } else {
    // ---------- conv2 (R6-proven structure) ----------
    int lane = tid & 63, wave = tid >> 6;
    int p = (blockIdx.x - 792)*64 + lane;        // 396*64 = 25344
    int i = p/132, j = p%132;
    float acc[6] = {0.f,0.f,0.f,0.f,0.f,0.f};
    int cbase = wave*32;
    #pragma unroll
    for (int kh=0; kh<3; ++kh){
      int gi = i+kh-1;
      if ((unsigned)gi >= 192u) continue;
      #pragma unroll
      for (int kw=0; kw<3; ++kw){
        int gj = j+kw-1;
        if ((unsigned)gj >= 132u) continue;
        const float* row = LFF + (size_t)(gi*132+gj)*128 + cbase;
        int tap = kh*3+kw;
        #pragma unroll
        for (int cq=0; cq<8; ++cq){
          float4 v = *(const float4*)(row + cq*4);
          #pragma unroll
          for (int cls=0; cls<6; ++cls){
            float4 wv = *(const float4*)(W6 + (size_t)(cls*9+tap)*128 + cbase + cq*4);
            acc[cls] += v.x*wv.x + v.y*wv.y + v.z*wv.z + v.w*wv.w;
          }
        }
      }
    }
    float* red = smem;    // [4][6][64]
    #pragma unroll
    for (int c=0;c<6;++c) red[(wave*6+c)*64 + lane] = acc[c];
    __syncthreads();
    if (wave==0){
      #pragma unroll
      for (int c=0;c<6;++c){
        float s = red[c*64+lane] + red[(6+c)*64+lane] + red[(12+c)*64+lane] + red[(18+c)*64+lane] + bhm[c];
        HMS[(size_t)c*HW + p] = 1.f/(1.f+expf(-s));
      }
    }
  }
}

// ---------------- NMS + threshold + 16-bit histogram ----------------
__global__ __launch_bounds__(256) void k_nms(const float* __restrict__ HMS,
                                             float* __restrict__ VALS,
                                             int* __restrict__ HIST){
  int t = blockIdx.x*256 + threadIdx.x;   // 594*256 = 152064
  int c = t / HW, p = t % HW;
  int i = p/132, j = p%132;
  float h = HMS[t];
  float v;
  if (c < 3){
    v = 0.f;
    if (i>=1 && i<=190 && j>=1 && j<=130){
      float m = -1e30f;
      #pragma unroll
      for (int di=-1;di<=1;++di)
        #pragma unroll
        for (int dj=-1;dj<=1;++dj)
          m = fmaxf(m, HMS[(size_t)c*HW + (i+di)*132 + (j+dj)]);
      if (h == m) v = h;
    }
  } else v = h;
  if (!(v > 0.01f)) v = 0.f;
  VALS[t] = v;
  if (v > 0.f) atomicAdd(HIST + (__float_as_uint(v)>>16), 1);
}

// ---------------- level-1 scan: parallel suffix scan (R9-proven) ----------------
__global__ __launch_bounds__(1024) void k_scan(const int* __restrict__ HIST, int* __restrict__ SCAN){
  __shared__ int part[1024];
  __shared__ int gsel;
  int t = threadIdx.x;
  int s = 0, base = t*64;
  for (int u=0;u<64;++u) s += HIST[base+u];
  part[t] = s;
  __syncthreads();
  for (int off=1; off<1024; off<<=1){
    int add = (t+off < 1024) ? part[t+off] : 0;
    __syncthreads();
    part[t] += add;
    __syncthreads();
  }
  int total = part[0];
  int mineI = part[t];
  int nextI = (t < 1023) ? part[t+1] : 0;
  if (mineI >= NPROP && nextI < NPROP) gsel = t;
  if (t == 0 && total < NPROP) gsel = -1;
  __syncthreads();
  int g = gsel;
  if (g < 0){
    if (t==0){ SCAN[0] = 0; SCAN[1] = total; }
    return;
  }
  int cumG = (g < 1023) ? part[g+1] : 0;
  if (t < 64){
    int x = HIST[g*64 + t];
    #pragma unroll
    for (int off=1; off<64; off<<=1){
      int y = __shfl_down(x, off);
      x += (t + off < 64) ? y : 0;
    }
    int Snext = __shfl_down(x, 1);
    int incl  = cumG + x;
    int nextc = (t==63) ? cumG : cumG + Snext;
    if (incl >= NPROP && nextc < NPROP){
      SCAN[0] = g*64 + t;
      SCAN[1] = nextc;
    }
  }
}

// ---------------- collect candidates with bin >= bstar (one-level; CAP has 3-4x headroom) ----------
__global__ __launch_bounds__(256) void k_collect(const float* __restrict__ VALS,
                                                 const int* __restrict__ SCAN,
                                                 int* __restrict__ CNT,
                                                 float* __restrict__ CV, int* __restrict__ CI){
  int t = blockIdx.x*256 + threadIdx.x;   // 594*256 = 152064
  float v = VALS[t];
  int bstar = SCAN[0];
  if (v > 0.f && (int)(__float_as_uint(v)>>16) >= bstar){
    int pos = atomicAdd(CNT, 1);
    if (pos < CAP){ CV[pos] = v; CI[pos] = t; }
  }
}

// ---------------- bitonic sort candidates (2048), take top-500 ----------------
__global__ __launch_bounds__(1024) void k_sort(const float* __restrict__ CV, const int* __restrict__ CI,
                                               const int* __restrict__ CNT,
                                               int* __restrict__ TOPS, int* __restrict__ TOPC){
  __shared__ float sv[CAP];
  __shared__ int   si[CAP];
  int tid = threadIdx.x;
  int M = imin(CNT[0], CAP);
  for (int i=tid; i<CAP; i+=1024){
    if (i < M){ sv[i] = CV[i]; si[i] = CI[i]; }
    else      { sv[i] = -1.f;  si[i] = 0x7fffffff; }
  }
  __syncthreads();
  for (int k=2; k<=CAP; k<<=1){
    for (int j=k>>1; j>0; j>>=1){
      for (int i=tid; i<CAP; i+=1024){
        int p = i ^ j;
        if (p > i){
          bool up = ((i & k) == 0);
          float va = sv[i], vb = sv[p];
          int ia = si[i], ib = si[p];
          bool aFirst = (va > vb) || (va == vb && ia < ib);
          bool bFirst = (vb > va) || (vb == va && ib < ia);
          bool doswap = up ? bFirst : aFirst;
          if (doswap){ sv[i]=vb; sv[p]=va; si[i]=ib; si[p]=ia; }
        }
      }
      __syncthreads();
    }
  }
  for (int t=tid; t<NPROP; t+=1024){
    int idx = imin(si[t], NCLS*HW - 1);
    TOPC[t] = idx / HW;
    TOPS[t] = idx % HW;
  }
}

// ---------------- fused qbuild + attention + LN/FFN/LN + heads + decode (R9-proven) ----------
__global__ __launch_bounds__(256) void k_attn(const float* __restrict__ KK, const float* __restrict__ VV,
                                              const float* __restrict__ LFF,
                                              const int* __restrict__ TOPS, const int* __restrict__ TOPC,
                                              const float* __restrict__ Wcls, const float* __restrict__ bcls,
                                              const float* __restrict__ pW1, const float* __restrict__ pb1,
                                              const float* __restrict__ pW2, const float* __restrict__ pb2,
                                              const float* __restrict__ Wq, const float* __restrict__ bq,
                                              const float* __restrict__ Wo, const float* __restrict__ bo,
                                              const float* __restrict__ g1, const float* __restrict__ b1,
                                              const float* __restrict__ Wf1, const float* __restrict__ bf1,
                                              const float* __restrict__ Wf2, const float* __restrict__ bf2,
                                              const float* __restrict__ g2, const float* __restrict__ b2,
                                              const float* __restrict__ Wc, const float* __restrict__ bc,
                                              const float* __restrict__ Wh, const float* __restrict__ bh,
                                              const float* __restrict__ Wd, const float* __restrict__ bd,
                                              const float* __restrict__ Wr, const float* __restrict__ br,
                                              const float* __restrict__ Whm2, const float* __restrict__ bhm2,
                                              float* __restrict__ out){
  int n = blockIdx.x, tid = threadIdx.x;
  __shared__ __align__(16) float qhL[128];
  __shared__ float sc[8*441];                 // scores; also split-k partial scratch
  __shared__ int   kiL[441];
  __shared__ __align__(16) float ctxL[128];
  __shared__ float xL[128];
  __shared__ float hidL[256];
  __shared__ float sumsL[8];
  __shared__ float stat[2];
  __shared__ float dots[16];
  int sp = TOPS[n];
  int cls = TOPC[n];
  const int kb64 = (tid>>7)*64, c128 = tid&127;
  float qreg = 0.f;
  if (tid < 128){
    float qx = (float)(sp/132)+0.5f, qy = (float)(sp%132)+0.5f;
    ctxL[tid] = fmaxf(qx*pW1[tid] + qy*pW1[128+tid] + pb1[tid], 0.f);
    qreg = LFF[(size_t)sp*128+tid] + Wcls[tid*6+cls] + bcls[tid];
  }
  __syncthreads();
  {
    float pe = 0.f;
    for (int k=kb64; k<kb64+64; ++k) pe += ctxL[k]*pW2[(size_t)k*128+c128];
    sc[tid] = pe;
  }
  __syncthreads();
  if (tid < 128) xL[tid] = qreg + pb2[tid] + sc[tid] + sc[tid+128];
  __syncthreads();
  {
    float qh = 0.f;
    for (int k=kb64; k<kb64+64; ++k) qh += xL[k]*Wq[(size_t)k*128+c128];
    sc[tid] = qh;
  }
  __syncthreads();
  if (tid < 128) qhL[tid] = bq[tid] + sc[tid] + sc[tid+128];
  __syncthreads();
  int spx = sp/192, spy = sp%132;       // faithful to ref's //X_GRID, %Y_GRID
  for (int l = tid; l < 441; l += 256){
    int a = l/21, bb = l%21;
    int kidx = (spx + a - 10)*192 + (spy + bb - 10);
    bool msk = (kidx < 0) || (kidx >= HW);
    int kc = imin(imax(kidx,0), HW-1);
    kiL[l] = kc;
    const float4* kk4 = (const float4*)(KK + (size_t)kc*128);
    const float4* qh4 = (const float4*)qhL;
    #pragma unroll
    for (int hh=0; hh<8; ++hh){
      float acc = 0.f;
      #pragma unroll
      for (int d4=0; d4<4; ++d4){
        float4 kv = kk4[hh*4+d4]; float4 qv = qh4[hh*4+d4];
        acc += kv.x*qv.x + kv.y*qv.y + kv.z*qv.z + kv.w*qv.w;
      }
      sc[hh*441+l] = msk ? -1e9f : acc*0.25f;
    }
  }
  __syncthreads();
  int wave = tid>>6, lane = tid&63;
  for (int hh = wave; hh < 8; hh += 4){
    float mx = -3.0e38f;
    for (int l = lane; l < 441; l += 64) mx = fmaxf(mx, sc[hh*441+l]);
    #pragma unroll
    for (int off=32; off; off>>=1) mx = fmaxf(mx, __shfl_xor(mx, off));
    float sum = 0.f;
    for (int l = lane; l < 441; l += 64){
      float e = __expf(sc[hh*441+l] - mx);
      sc[hh*441+l] = e; sum += e;
    }
    #pragma unroll
    for (int off=32; off; off>>=1) sum += __shfl_xor(sum, off);
    if (lane==0) sumsL[hh] = sum;
  }
  __syncthreads();
  for (int hh = wave; hh < 8; hh += 4){
    float a[16];
    #pragma unroll
    for (int d=0; d<16; ++d) a[d]=0.f;
    for (int l = lane; l < 441; l += 64){
      float w = sc[hh*441+l];
      const float4* vv4 = (const float4*)(VV + (size_t)kiL[l]*128 + hh*16);
      #pragma unroll
      for (int d4=0; d4<4; ++d4){
        float4 v = vv4[d4];
        a[d4*4+0]+=w*v.x; a[d4*4+1]+=w*v.y; a[d4*4+2]+=w*v.z; a[d4*4+3]+=w*v.w;
      }
    }
    #pragma unroll
    for (int d=0; d<16; ++d){
      #pragma unroll
      for (int off=32; off; off>>=1) a[d] += __shfl_xor(a[d], off);
    }
    if (lane==0){
      float inv = 1.f/sumsL[hh];
      #pragma unroll
      for (int d=0; d<16; ++d) ctxL[hh*16+d] = a[d]*inv;
    }
  }
  __syncthreads();
  {
    float acc = 0.f;
    for (int k=kb64; k<kb64+64; ++k) acc += ctxL[k]*Wo[(size_t)k*128+c128];
    sc[tid] = acc;
  }
  __syncthreads();
  float x1v = 0.f;
  if (tid < 128){
    x1v = qreg + bo[tid] + sc[tid] + sc[tid+128];
    xL[tid] = x1v;
  }
  __syncthreads();
  if (tid < 64){
    float u0 = xL[tid], u1 = xL[tid+64];
    float s = u0+u1, s2 = u0*u0+u1*u1;
    #pragma unroll
    for (int off=32; off; off>>=1){ s += __shfl_xor(s, off); s2 += __shfl_xor(s2, off); }
    if (tid==0){ float mean = s*(1.f/128.f); float var = s2*(1.f/128.f) - mean*mean;
      stat[0]=mean; stat[1]=rsqrtf(var + 1e-5f); }
  }
  __syncthreads();
  if (tid < 128) xL[tid] = (x1v - stat[0])*stat[1]*g1[tid] + b1[tid];
  __syncthreads();
  {
    float hv = bf1[tid];
    for (int k=0;k<128;++k) hv += xL[k]*Wf1[(size_t)k*256+tid];
    hidL[tid] = fmaxf(hv, 0.f);
  }
  __syncthreads();
  {
    int kb = (tid>>7)*128;
    float acc = 0.f;
    for (int k=kb; k<kb+128; ++k) acc += hidL[k]*Wf2[(size_t)k*128+c128];
    sc[tid] = acc;
  }
  __syncthreads();
  float x2v = 0.f;
  if (tid < 128) x2v = xL[tid] + bf2[tid] + sc[tid] + sc[tid+128];
  __syncthreads();
  if (tid < 128) hidL[tid] = x2v;
  __syncthreads();
  if (tid < 64){
    float u0 = hidL[tid], u1 = hidL[tid+64];
    float s = u0+u1, s2 = u0*u0+u1*u1;
    #pragma unroll
    for (int off=32; off; off>>=1){ s += __shfl_xor(s, off); s2 += __shfl_xor(s2, off); }
    if (tid==0){ float mean = s*(1.f/128.f); float var = s2*(1.f/128.f) - mean*mean;
      stat[0]=mean; stat[1]=rsqrtf(var + 1e-5f); }
  }
  __syncthreads();
  if (tid < 128) xL[tid] = (x2v - stat[0])*stat[1]*g2[tid] + b2[tid];   // final x2
  __syncthreads();
  if (tid < 14){
    const float* Wp; float bb;
    if (tid < 2)      { Wp = Wc + tid*128;        bb = bc[tid];      }
    else if (tid < 3) { Wp = Wh;                  bb = bh[0];        }
    else if (tid < 6) { Wp = Wd + (tid-3)*128;    bb = bd[tid-3];    }
    else if (tid < 8) { Wp = Wr + (tid-6)*128;    bb = br[tid-6];    }
    else              { Wp = Whm2 + (tid-8)*128;  bb = bhm2[tid-8];  }
    float acc = bb;
    for (int k=0;k<128;++k) acc += xL[k]*Wp[k];
    dots[tid] = acc;
  }
  __syncthreads();
  if (tid == 0){
    float qpx = (float)(sp/132)+0.5f, qpy = (float)(sp%132)+0.5f;
    float cx = (dots[0]+qpx)*0.64f - 61.44f;
    float cy = (dots[1]+qpy)*0.64f - 42.24f;
    float e0 = expf(dots[3]), e1 = expf(dots[4]), e2 = expf(dots[5]);
    float hgt = dots[2] - e2*0.5f;
    float rot = atanf(dots[6]/(dots[7] + 1e-6f));
    float bestv = -1.f; int bestc = 0;
    #pragma unroll
    for (int m=0;m<6;++m){
      float s = 1.f/(1.f + expf(-dots[8+m]));
      if (s > bestv){ bestv = s; bestc = m; }
    }
    float* o = out + (size_t)n*9;
    o[0]=cx; o[1]=cy; o[2]=hgt; o[3]=e0; o[4]=e1; o[5]=e2; o[6]=rot;
    o[7]=(float)bestc; o[8]=bestv;
  }
}

// ---------------- launcher ----------------
extern "C" void kernel_launch(void* const* d_in, const int* in_sizes, int n_in,
                              void* d_out, int out_size, void* d_ws, size_t ws_size,
                              hipStream_t stream){
  (void)in_sizes; (void)n_in; (void)out_size;
  const float* IN   = (const float*)d_in[0];
  const float* Wsh  = (const float*)d_in[1];
  const float* bsh  = (const float*)d_in[2];
  const float* Whm  = (const float*)d_in[3];
  const float* bhm  = (const float*)d_in[4];
  const float* Wcls = (const float*)d_in[5];
  const float* bcls = (const float*)d_in[6];
  const float* Wp1  = (const float*)d_in[7];
  const float* bp1  = (const float*)d_in[8];
  const float* Wp2  = (const float*)d_in[9];
  const float* bp2  = (const float*)d_in[10];
  const float* Wq   = (const float*)d_in[11];
  const float* bq   = (const float*)d_in[12];
  const float* Wk   = (const float*)d_in[13];
  const float* bk   = (const float*)d_in[14];
  const float* Wv   = (const float*)d_in[15];
  const float* bv   = (const float*)d_in[16];
  const float* Wo   = (const float*)d_in[17];
  const float* bo   = (const float*)d_in[18];
  const float* g1   = (const float*)d_in[19];
  const float* b1   = (const float*)d_in[20];
  const float* g2   = (const float*)d_in[21];
  const float* b2   = (const float*)d_in[22];
  const float* Wf1  = (const float*)d_in[23];
  const float* bf1  = (const float*)d_in[24];
  const float* Wf2  = (const float*)d_in[25];
  const float* bf2  = (const float*)d_in[26];
  const float* Wc   = (const float*)d_in[27];
  const float* bc   = (const float*)d_in[28];
  const float* Wh   = (const float*)d_in[29];
  const float* bh   = (const float*)d_in[30];
  const float* Wd   = (const float*)d_in[31];
  const float* bd   = (const float*)d_in[32];
  const float* Wr   = (const float*)d_in[33];
  const float* br   = (const float*)d_in[34];
  const float* Whm2 = (const float*)d_in[37];
  const float* bhm2 = (const float*)d_in[38];
  float* out = (float*)d_out;
  float* W = (float*)d_ws;

  const size_t N_LFF  = (size_t)HW*128;
  const size_t OFF_LFF  = 0;
  const size_t OFF_PE   = OFF_LFF + N_LFF;         // conv1 partial g1
  const size_t OFF_KK   = OFF_PE + N_LFF;          // conv1 partial g2, then KK
  const size_t OFF_VV   = OFF_KK + N_LFF;          // conv1 partial g3, then VV
  const size_t OFF_WT   = OFF_VV + N_LFF;          // 294912
  const size_t OFF_WHMT = OFF_WT + 294912;         // 6912
  const size_t OFF_HMS  = OFF_WHMT + 6912;         // 152064
  const size_t OFF_VALS = OFF_HMS + 152064;        // 152064
  const size_t OFF_HIST = OFF_VALS + 152064;       // 65536
  const size_t OFF_SCAN = OFF_HIST + 65536;        // 16
  const size_t OFF_CNT  = OFF_SCAN + 16;           // 16
  const size_t OFF_CV   = OFF_CNT + 16;            // CAP
  const size_t OFF_CI   = OFF_CV + CAP;            // CAP
  const size_t OFF_TOPS = OFF_CI + CAP;            // 512
  const size_t OFF_TOPC = OFF_TOPS + 512;          // 512
  const size_t TOTAL    = OFF_TOPC + 512;
  if (ws_size < TOTAL*sizeof(float)) return;

  // k_wt also zeroes HIST|SCAN|CNT (65568 ints, contiguous at OFF_HIST)
  k_wt    <<<1152, 256, 0, stream>>>(Wsh, Whm, W+OFF_WT, W+OFF_WHMT, (int*)(W+OFF_HIST));
  k_conv1 <<<dim3(396,4), 256, 0, stream>>>(IN, W+OFF_WT, W+OFF_LFF, W+OFF_PE, W+OFF_KK, W+OFF_VV);
  k_cadd  <<<3168, 256, 0, stream>>>(W+OFF_LFF, W+OFF_PE, W+OFF_KK, W+OFF_VV, bsh);
  k_mid   <<<1188, 256, 0, stream>>>(W+OFF_LFF, Wp1, bp1, Wp2, bp2, Wk, bk, Wv, bv,
                                     W+OFF_KK, W+OFF_VV, W+OFF_WHMT, bhm, W+OFF_HMS);
  k_nms   <<<594,  256, 0, stream>>>(W+OFF_HMS, W+OFF_VALS, (int*)(W+OFF_HIST));
  k_scan  <<<1,   1024, 0, stream>>>((const int*)(W+OFF_HIST), (int*)(W+OFF_SCAN));
  k_collect<<<594, 256, 0, stream>>>(W+OFF_VALS, (const int*)(W+OFF_SCAN),
                                     (int*)(W+OFF_CNT), W+OFF_CV, (int*)(W+OFF_CI));
  k_sort  <<<1,   1024, 0, stream>>>(W+OFF_CV, (const int*)(W+OFF_CI), (const int*)(W+OFF_CNT),
                                     (int*)(W+OFF_TOPS), (int*)(W+OFF_TOPC));
  k_attn  <<<500,  256, 0, stream>>>(W+OFF_KK, W+OFF_VV, W+OFF_LFF,
                                     (const int*)(W+OFF_TOPS), (const int*)(W+OFF_TOPC),
                                     Wcls, bcls, Wp1, bp1, Wp2, bp2, Wq, bq,
                                     Wo, bo, g1, b1, Wf1, bf1, Wf2, bf2, g2, b2,
                                     Wc, bc, Wh, bh, Wd, bd, Wr, br, Whm2, bhm2, out);
}

// Round 11
// 583.287 us; speedup vs baseline: 1.2527x; 1.1302x over previous
//
#include <hip/hip_runtime.h>
#include <math.h>
#include <float.h>

#define XG 192
#define YG 132
#define HW 25344           // 192*132
#define NCLS 6
#define NPROP 500
#define LWIN 441
#define CAP 2048           // candidate cap for top-k sort (one-level select)

static __device__ __forceinline__ int imin(int a,int b){return a<b?a:b;}
static __device__ __forceinline__ int imax(int a,int b){return a>b?a:b;}

// async global->LDS, 16B per lane; LDS dest is wave-uniform base + lane*16
__device__ __forceinline__ void gl_lds16(const float* gp, float* lp){
  __builtin_amdgcn_global_load_lds(
      (const __attribute__((address_space(1))) unsigned int*)gp,
      (__attribute__((address_space(3))) unsigned int*)lp,
      16, 0, 0);
}

// ---------------- weight transposes (output-indexed: coalesced writes) + zeroing ----------------
// WT / W6 as before; plus k-contiguous transposes for k_attn's GEMV phases:
// WQT[c*128+k]=Wq[k*128+c]  WP2T[c*128+k]=Wp2[k*128+c]  WOT[c*128+k]=Wo[k*128+c]
// WF1T[o*128+k]=Wf1[k*256+o]  WF2T[c*256+k]=Wf2[k*128+c]
__global__ __launch_bounds__(256) void k_wt(const float* __restrict__ Ws,
                                            const float* __restrict__ Whm,
                                            const float* __restrict__ Wq,
                                            const float* __restrict__ Wp2,
                                            const float* __restrict__ Wo,
                                            const float* __restrict__ Wf1,
                                            const float* __restrict__ Wf2,
                                            float* __restrict__ WT,
                                            float* __restrict__ W6,
                                            float* __restrict__ WQT,
                                            float* __restrict__ WP2T,
                                            float* __restrict__ WOT,
                                            float* __restrict__ WF1T,
                                            float* __restrict__ WF2T,
                                            int* __restrict__ Z){
  int t = blockIdx.x*256 + threadIdx.x;
  if (t < 294912){
    int oc = t & 127, m = t >> 7;
    WT[t] = Ws[(size_t)oc*2304 + m];
  }
  if (t < 6912){
    int c = t & 127, row = t >> 7;      // row = cls*9+tap, 54 rows
    int cls = row / 9, tap = row % 9;
    W6[t] = Whm[(size_t)cls*1152 + c*9 + tap];
  }
  if (t < 16384){
    int k = t & 127, c = t >> 7;
    WQT[t]  = Wq [(size_t)k*128 + c];
    WP2T[t] = Wp2[(size_t)k*128 + c];
    WOT[t]  = Wo [(size_t)k*128 + c];
  }
  if (t < 32768){
    { int k = t & 127, o = t >> 7;  WF1T[t] = Wf1[(size_t)k*256 + o]; }
    { int k = t & 255, c = t >> 8;  WF2T[t] = Wf2[(size_t)k*128 + c]; }
  }
  if (t < 65568) Z[t] = 0;              // HIST 65536 | SCAN 16 | CNT 16
}

// ---------------- conv1 v8 (R8/R10-proven 209us): store-coalesced, 256 threads ----------------
__global__ __launch_bounds__(256, 4) void k_conv1(const float* __restrict__ IN,
                                                  const float* __restrict__ WT,
                                                  float* __restrict__ O0, float* __restrict__ O1,
                                                  float* __restrict__ O2, float* __restrict__ O3){
  const int b  = blockIdx.x;
  const int g  = blockIdx.y;
  const int i0 = (b % 3) * 64;
  const int j  = b / 3;
  const int tid = threadIdx.x;
  const int wv  = tid >> 6;
  const int oc0 = (tid & 31) * 4;
  const int pxs = tid >> 5;            // 0..7
  __shared__ float wlds[4608];         // 4cc x 9tap x 128oc
  __shared__ float hlds[816];          // 4cc x 3rows x 68 (padded, 16B-aligned rows)
  float4 acc[8];
  #pragma unroll
  for (int px=0;px<8;++px) acc[px] = make_float4(0.f,0.f,0.f,0.f);
  const int C0g = g*64;
  for (int q=0; q<16; ++q){
    __syncthreads();
    const float* wchunk = WT + (size_t)(C0g + q*4)*1152;
    #pragma unroll
    for (int r=0; r<4; ++r)
      gl_lds16(wchunk + (size_t)(r*256 + tid)*4, wlds + (size_t)(r*256 + wv*64)*4);
    if (wv < 2)
      gl_lds16(wchunk + (size_t)(1024 + tid)*4, wlds + (size_t)(1024 + wv*64)*4);
    for (int e=tid; e<792; e+=256){
      int cc = e/198, rem = e%198, r = rem/66, ii = rem%66;
      int gj = j-1+r, gi = i0-1+ii;
      float v = 0.f;
      if ((unsigned)gj < 132u && (unsigned)gi < 192u)
        v = IN[(size_t)(C0g+q*4+cc)*25344 + gj*192 + gi];
      hlds[cc*204 + r*68 + ii] = v;
    }
    __syncthreads();
    for (int cc=0; cc<4; ++cc){
      const float* hb = hlds + cc*204 + pxs*8;
      const float* wb = wlds + cc*1152 + oc0;
      float a[3][10];
      #pragma unroll
      for (int r=0;r<3;++r)
        #pragma unroll
        for (int v=0; v<10; ++v) a[r][v] = hb[r*68 + v];
      #pragma unroll
      for (int kh=0;kh<3;++kh){
        #pragma unroll
        for (int kw=0;kw<3;++kw){
          float4 w = *(const float4*)(wb + (kh*3+kw)*128);
          #pragma unroll
          for (int px=0;px<8;++px){
            float act = a[kw][px+kh];
            acc[px].x += act*w.x;
            acc[px].y += act*w.y;
            acc[px].z += act*w.z;
            acc[px].w += act*w.w;
          }
        }
      }
    }
  }
  float* dst = (g==0)?O0:((g==1)?O1:((g==2)?O2:O3));
  #pragma unroll
  for (int px=0;px<8;++px){
    int p = (i0 + pxs*8 + px)*132 + j;
    *(float4*)(dst + (size_t)p*128 + oc0) = acc[px];
  }
}

// ---------------- combine 4 k-split partials + bias + relu ----------------
__global__ __launch_bounds__(256) void k_cadd(float* __restrict__ LFF,
                                              const float* __restrict__ P1,
                                              const float* __restrict__ P2,
                                              const float* __restrict__ P3,
                                              const float* __restrict__ bias){
  int t = blockIdx.x*256 + threadIdx.x;   // 3168*256 = 811008 float4s
  float4 a = ((const float4*)LFF)[t];
  float4 b = ((const float4*)P1)[t];
  float4 c = ((const float4*)P2)[t];
  float4 d = ((const float4*)P3)[t];
  float4 bs = ((const float4*)bias)[t & 31];
  float4 r;
  r.x = fmaxf(a.x+b.x+c.x+d.x+bs.x, 0.f);
  r.y = fmaxf(a.y+b.y+c.y+d.y+bs.y, 0.f);
  r.z = fmaxf(a.z+b.z+c.z+d.z+bs.z, 0.f);
  r.w = fmaxf(a.w+b.w+c.w+d.w+bs.w, 0.f);
  ((float4*)LFF)[t] = r;
}

// ---------------- fused (kkvv | conv2) ; both weight paths LDS-staged ----------------
// blocks 0..791: kkvv (32 px each). blocks 792..1187: conv2 (64 px each, W6 in LDS).
__global__ __launch_bounds__(256) void k_mid(const float* __restrict__ LFF,
                                             const float* __restrict__ W1, const float* __restrict__ b1,
                                             const float* __restrict__ W2, const float* __restrict__ b2,
                                             const float* __restrict__ Wk, const float* __restrict__ bk,
                                             const float* __restrict__ Wv, const float* __restrict__ bv,
                                             float* __restrict__ KK, float* __restrict__ VV,
                                             const float* __restrict__ W6, const float* __restrict__ bhm,
                                             float* __restrict__ HMS){
  __shared__ float smem[12288];   // kkvv: hs 4096 | sf 4096 | wbuf 4096 (48KB)
  const int tid = threadIdx.x;
  const int wv4 = tid >> 6;
  if (blockIdx.x < 792){
    // ---------- kkvv (R10-proven) ----------
    float* hs   = smem;
    float* sf   = smem + 4096;
    float* wbuf = smem + 8192;
    const int p0 = blockIdx.x*32;
    for (int e=tid; e<4096; e+=256){
      int k = e>>5, px = e&31;
      int p = p0+px;
      float bx = (float)(p/132)+0.5f, by = (float)(p%132)+0.5f;
      hs[k*32+px] = fmaxf(bx*W1[k] + by*W1[128+k] + b1[k], 0.f);
    }
    for (int e=tid; e<4096; e+=256){
      int px = e>>7, k = e&127;
      sf[k*32+px] = LFF[(size_t)(p0+px)*128 + k];
    }
    const int pxg = tid & 15, ocg = tid >> 4;   // 16 x 16
    const int px0 = pxg*2, oc0 = ocg*8;
    float accA[2][8];
    #pragma unroll
    for (int r=0;r<2;++r)
      #pragma unroll
      for (int u=0;u<8;++u) accA[r][u]=0.f;
    for (int c0=0; c0<128; c0+=32){
      __syncthreads();
      const float* wsrc = W2 + (size_t)c0*128;
      #pragma unroll
      for (int r=0;r<4;++r)
        gl_lds16(wsrc + (size_t)(r*256+tid)*4, wbuf + (size_t)(r*256+wv4*64)*4);
      __syncthreads();
      #pragma unroll 2
      for (int k=0;k<32;++k){
        float a0 = hs[(c0+k)*32+px0], a1 = hs[(c0+k)*32+px0+1];
        const float4* w = (const float4*)(wbuf + (size_t)k*128 + oc0);
        float4 w0 = w[0], w1 = w[1];
        accA[0][0]+=a0*w0.x; accA[0][1]+=a0*w0.y; accA[0][2]+=a0*w0.z; accA[0][3]+=a0*w0.w;
        accA[0][4]+=a0*w1.x; accA[0][5]+=a0*w1.y; accA[0][6]+=a0*w1.z; accA[0][7]+=a0*w1.w;
        accA[1][0]+=a1*w0.x; accA[1][1]+=a1*w0.y; accA[1][2]+=a1*w0.z; accA[1][3]+=a1*w0.w;
        accA[1][4]+=a1*w1.x; accA[1][5]+=a1*w1.y; accA[1][6]+=a1*w1.z; accA[1][7]+=a1*w1.w;
      }
    }
    __syncthreads();
    #pragma unroll
    for (int u=0;u<8;++u){
      float bb = b2[oc0+u];
      hs[(oc0+u)*32+px0]   = sf[(oc0+u)*32+px0]   + accA[0][u] + bb;
      hs[(oc0+u)*32+px0+1] = sf[(oc0+u)*32+px0+1] + accA[1][u] + bb;
    }
    float accK[2][8], accV[2][8];
    #pragma unroll
    for (int u=0;u<8;++u){
      float k0 = bk[oc0+u], v0 = bv[oc0+u];
      accK[0][u]=k0; accK[1][u]=k0; accV[0][u]=v0; accV[1][u]=v0;
    }
    for (int c0=0; c0<128; c0+=16){
      __syncthreads();
      #pragma unroll
      for (int r=0;r<2;++r){
        gl_lds16(Wk + (size_t)c0*128 + (size_t)(r*256+tid)*4, wbuf + (size_t)(r*256+wv4*64)*4);
        gl_lds16(Wv + (size_t)c0*128 + (size_t)(r*256+tid)*4, wbuf + 2048 + (size_t)(r*256+wv4*64)*4);
      }
      __syncthreads();
      #pragma unroll 2
      for (int k=0;k<16;++k){
        int kk = c0+k;
        float s0 = hs[kk*32+px0], s1 = hs[kk*32+px0+1];
        float f0 = sf[kk*32+px0], f1 = sf[kk*32+px0+1];
        const float4* wkp = (const float4*)(wbuf + (size_t)k*128 + oc0);
        const float4* wvp = (const float4*)(wbuf + 2048 + (size_t)k*128 + oc0);
        float4 k0v = wkp[0], k1v = wkp[1], v0v = wvp[0], v1v = wvp[1];
        accK[0][0]+=s0*k0v.x; accK[0][1]+=s0*k0v.y; accK[0][2]+=s0*k0v.z; accK[0][3]+=s0*k0v.w;
        accK[0][4]+=s0*k1v.x; accK[0][5]+=s0*k1v.y; accK[0][6]+=s0*k1v.z; accK[0][7]+=s0*k1v.w;
        accK[1][0]+=s1*k0v.x; accK[1][1]+=s1*k0v.y; accK[1][2]+=s1*k0v.z; accK[1][3]+=s1*k0v.w;
        accK[1][4]+=s1*k1v.x; accK[1][5]+=s1*k1v.y; accK[1][6]+=s1*k1v.z; accK[1][7]+=s1*k1v.w;
        accV[0][0]+=f0*v0v.x; accV[0][1]+=f0*v0v.y; accV[0][2]+=f0*v0v.z; accV[0][3]+=f0*v0v.w;
        accV[0][4]+=f0*v1v.x; accV[0][5]+=f0*v1v.y; accV[0][6]+=f0*v1v.z; accV[0][7]+=f0*v1v.w;
        accV[1][0]+=f1*v0v.x; accV[1][1]+=f1*v0v.y; accV[1][2]+=f1*v0v.z; accV[1][3]+=f1*v0v.w;
        accV[1][4]+=f1*v1v.x; accV[1][5]+=f1*v1v.y; accV[1][6]+=f1*v1v.z; accV[1][7]+=f1*v1v.w;
      }
    }
    #pragma unroll
    for (int r=0;r<2;++r){
      int p = p0+px0+r;
      float4* oK = (float4*)(KK + (size_t)p*128 + oc0);
      float4* oV = (float4*)(VV + (size_t)p*128 + oc0);
      float4 t0, t1;
      t0.x=accK[r][0]; t0.y=accK[r][1]; t0.z=accK[r][2]; t0.w=accK[r][3];
      t1.x=accK[r][4]; t1.y=accK[r][5]; t1.z=accK[r][6]; t1.w=accK[r][7];
      oK[0]=t0; oK[1]=t1;
      t0.x=accV[r][0]; t0.y=accV[r][1]; t0.z=accV[r][2]; t0.w=accV[r][3];
      t1.x=accV[r][4]; t1.y=accV[r][5]; t1.z=accV[r][6]; t1.w=accV[r][7];
      oV[0]=t0; oV[1]=t1;
    }
  } else {
    // ---------- conv2: W6 staged in LDS (was 432 global float4 loads/thread) ----------
    float* w6s = smem;          // 6912 floats
    float* red = smem + 8192;   // [4][6][64] = 1536 floats
    for (int e=tid; e<6912; e+=256) w6s[e] = W6[e];
    __syncthreads();
    int lane = tid & 63, wave = tid >> 6;
    int p = (blockIdx.x - 792)*64 + lane;        // 396*64 = 25344
    int i = p/132, j = p%132;
    float acc[6] = {0.f,0.f,0.f,0.f,0.f,0.f};
    int cbase = wave*32;
    #pragma unroll
    for (int kh=0; kh<3; ++kh){
      int gi = i+kh-1;
      if ((unsigned)gi >= 192u) continue;
      #pragma unroll
      for (int kw=0; kw<3; ++kw){
        int gj = j+kw-1;
        if ((unsigned)gj >= 132u) continue;
        const float* row = LFF + (size_t)(gi*132+gj)*128 + cbase;
        int tap = kh*3+kw;
        #pragma unroll
        for (int cq=0; cq<8; ++cq){
          float4 v = *(const float4*)(row + cq*4);
          #pragma unroll
          for (int cls=0; cls<6; ++cls){
            float4 wv = *(const float4*)(w6s + (size_t)(cls*9+tap)*128 + cbase + cq*4);
            acc[cls] += v.x*wv.x + v.y*wv.y + v.z*wv.z + v.w*wv.w;
          }
        }
      }
    }
    __syncthreads();
    #pragma unroll
    for (int c=0;c<6;++c) red[(wave*6+c)*64 + lane] = acc[c];
    __syncthreads();
    if (wave==0){
      #pragma unroll
      for (int c=0;c<6;++c){
        float s = red[c*64+lane] + red[(6+c)*64+lane] + red[(12+c)*64+lane] + red[(18+c)*64+lane] + bhm[c];
        HMS[(size_t)c*HW + p] = 1.f/(1.f+expf(-s));
      }
    }
  }
}

// ---------------- NMS + threshold + 16-bit histogram ----------------
__global__ __launch_bounds__(256) void k_nms(const float* __restrict__ HMS,
                                             float* __restrict__ VALS,
                                             int* __restrict__ HIST){
  int t = blockIdx.x*256 + threadIdx.x;   // 594*256 = 152064
  int c = t / HW, p = t % HW;
  int i = p/132, j = p%132;
  float h = HMS[t];
  float v;
  if (c < 3){
    v = 0.f;
    if (i>=1 && i<=190 && j>=1 && j<=130){
      float m = -1e30f;
      #pragma unroll
      for (int di=-1;di<=1;++di)
        #pragma unroll
        for (int dj=-1;dj<=1;++dj)
          m = fmaxf(m, HMS[(size_t)c*HW + (i+di)*132 + (j+dj)]);
      if (h == m) v = h;
    }
  } else v = h;
  if (!(v > 0.01f)) v = 0.f;
  VALS[t] = v;
  if (v > 0.f) atomicAdd(HIST + (__float_as_uint(v)>>16), 1);
}

// ---------------- level-1 scan: parallel suffix scan (R9-proven) ----------------
__global__ __launch_bounds__(1024) void k_scan(const int* __restrict__ HIST, int* __restrict__ SCAN){
  __shared__ int part[1024];
  __shared__ int gsel;
  int t = threadIdx.x;
  int s = 0, base = t*64;
  for (int u=0;u<64;++u) s += HIST[base+u];
  part[t] = s;
  __syncthreads();
  for (int off=1; off<1024; off<<=1){
    int add = (t+off < 1024) ? part[t+off] : 0;
    __syncthreads();
    part[t] += add;
    __syncthreads();
  }
  int total = part[0];
  int mineI = part[t];
  int nextI = (t < 1023) ? part[t+1] : 0;
  if (mineI >= NPROP && nextI < NPROP) gsel = t;
  if (t == 0 && total < NPROP) gsel = -1;
  __syncthreads();
  int g = gsel;
  if (g < 0){
    if (t==0){ SCAN[0] = 0; SCAN[1] = total; }
    return;
  }
  int cumG = (g < 1023) ? part[g+1] : 0;
  if (t < 64){
    int x = HIST[g*64 + t];
    #pragma unroll
    for (int off=1; off<64; off<<=1){
      int y = __shfl_down(x, off);
      x += (t + off < 64) ? y : 0;
    }
    int Snext = __shfl_down(x, 1);
    int incl  = cumG + x;
    int nextc = (t==63) ? cumG : cumG + Snext;
    if (incl >= NPROP && nextc < NPROP){
      SCAN[0] = g*64 + t;
      SCAN[1] = nextc;
    }
  }
}

// ---------------- collect candidates with bin >= bstar ----------------
__global__ __launch_bounds__(256) void k_collect(const float* __restrict__ VALS,
                                                 const int* __restrict__ SCAN,
                                                 int* __restrict__ CNT,
                                                 float* __restrict__ CV, int* __restrict__ CI){
  int t = blockIdx.x*256 + threadIdx.x;   // 594*256 = 152064
  float v = VALS[t];
  int bstar = SCAN[0];
  if (v > 0.f && (int)(__float_as_uint(v)>>16) >= bstar){
    int pos = atomicAdd(CNT, 1);
    if (pos < CAP){ CV[pos] = v; CI[pos] = t; }
  }
}

// ---------------- bitonic sort candidates (2048), take top-500 ----------------
__global__ __launch_bounds__(1024) void k_sort(const float* __restrict__ CV, const int* __restrict__ CI,
                                               const int* __restrict__ CNT,
                                               int* __restrict__ TOPS, int* __restrict__ TOPC){
  __shared__ float sv[CAP];
  __shared__ int   si[CAP];
  int tid = threadIdx.x;
  int M = imin(CNT[0], CAP);
  for (int i=tid; i<CAP; i+=1024){
    if (i < M){ sv[i] = CV[i]; si[i] = CI[i]; }
    else      { sv[i] = -1.f;  si[i] = 0x7fffffff; }
  }
  __syncthreads();
  for (int k=2; k<=CAP; k<<=1){
    for (int j=k>>1; j>0; j>>=1){
      for (int i=tid; i<CAP; i+=1024){
        int p = i ^ j;
        if (p > i){
          bool up = ((i & k) == 0);
          float va = sv[i], vb = sv[p];
          int ia = si[i], ib = si[p];
          bool aFirst = (va > vb) || (va == vb && ia < ib);
          bool bFirst = (vb > va) || (vb == va && ib < ia);
          bool doswap = up ? bFirst : aFirst;
          if (doswap){ sv[i]=vb; sv[p]=va; si[i]=ib; si[p]=ia; }
        }
      }
      __syncthreads();
    }
  }
  for (int t=tid; t<NPROP; t+=1024){
    int idx = imin(si[t], NCLS*HW - 1);
    TOPC[t] = idx / HW;
    TOPS[t] = idx % HW;
  }
}

// ---------------- fused qbuild + attention + LN/FFN/LN + heads + decode ----------------
// GEMV phases use k-contiguous transposed weights: 16-32 independent b128 loads/thread
// (was 64-128 serial b32 loads). FP summation order identical to previous rounds.
__global__ __launch_bounds__(256) void k_attn(const float* __restrict__ KK, const float* __restrict__ VV,
                                              const float* __restrict__ LFF,
                                              const int* __restrict__ TOPS, const int* __restrict__ TOPC,
                                              const float* __restrict__ Wcls, const float* __restrict__ bcls,
                                              const float* __restrict__ pW1, const float* __restrict__ pb1,
                                              const float* __restrict__ WP2T, const float* __restrict__ pb2,
                                              const float* __restrict__ WQT, const float* __restrict__ bq,
                                              const float* __restrict__ WOT, const float* __restrict__ bo,
                                              const float* __restrict__ g1, const float* __restrict__ b1,
                                              const float* __restrict__ WF1T, const float* __restrict__ bf1,
                                              const float* __restrict__ WF2T, const float* __restrict__ bf2,
                                              const float* __restrict__ g2, const float* __restrict__ b2,
                                              const float* __restrict__ Wc, const float* __restrict__ bc,
                                              const float* __restrict__ Wh, const float* __restrict__ bh,
                                              const float* __restrict__ Wd, const float* __restrict__ bd,
                                              const float* __restrict__ Wr, const float* __restrict__ br,
                                              const float* __restrict__ Whm2, const float* __restrict__ bhm2,
                                              float* __restrict__ out){
  int n = blockIdx.x, tid = threadIdx.x;
  __shared__ __align__(16) float qhL[128];
  __shared__ float sc[8*441];
  __shared__ int   kiL[441];
  __shared__ __align__(16) float ctxL[128];
  __shared__ float xL[128];
  __shared__ float hidL[256];
  __shared__ float sumsL[8];
  __shared__ float stat[2];
  __shared__ float dots[16];
  int sp = TOPS[n];
  int cls = TOPC[n];
  const int kb64 = (tid>>7)*64, c128 = tid&127;
  float qreg = 0.f;
  if (tid < 128){
    float qx = (float)(sp/132)+0.5f, qy = (float)(sp%132)+0.5f;
    ctxL[tid] = fmaxf(qx*pW1[tid] + qy*pW1[128+tid] + pb1[tid], 0.f);
    qreg = LFF[(size_t)sp*128+tid] + Wcls[tid*6+cls] + bcls[tid];
  }
  __syncthreads();
  {
    const float4* wp = (const float4*)(WP2T + (size_t)c128*128 + kb64);
    float pe = 0.f;
    #pragma unroll
    for (int k4=0;k4<16;++k4){
      float4 w = wp[k4]; int kb = kb64 + k4*4;
      pe += ctxL[kb]*w.x + ctxL[kb+1]*w.y + ctxL[kb+2]*w.z + ctxL[kb+3]*w.w;
    }
    sc[tid] = pe;
  }
  __syncthreads();
  if (tid < 128) xL[tid] = qreg + pb2[tid] + sc[tid] + sc[tid+128];
  __syncthreads();
  {
    const float4* wp = (const float4*)(WQT + (size_t)c128*128 + kb64);
    float qh = 0.f;
    #pragma unroll
    for (int k4=0;k4<16;++k4){
      float4 w = wp[k4]; int kb = kb64 + k4*4;
      qh += xL[kb]*w.x + xL[kb+1]*w.y + xL[kb+2]*w.z + xL[kb+3]*w.w;
    }
    sc[tid] = qh;
  }
  __syncthreads();
  if (tid < 128) qhL[tid] = bq[tid] + sc[tid] + sc[tid+128];
  __syncthreads();
  int spx = sp/192, spy = sp%132;       // faithful to ref's //X_GRID, %Y_GRID
  for (int l = tid; l < 441; l += 256){
    int a = l/21, bb = l%21;
    int kidx = (spx + a - 10)*192 + (spy + bb - 10);
    bool msk = (kidx < 0) || (kidx >= HW);
    int kc = imin(imax(kidx,0), HW-1);
    kiL[l] = kc;
    const float4* kk4 = (const float4*)(KK + (size_t)kc*128);
    const float4* qh4 = (const float4*)qhL;
    #pragma unroll
    for (int hh=0; hh<8; ++hh){
      float acc = 0.f;
      #pragma unroll
      for (int d4=0; d4<4; ++d4){
        float4 kv = kk4[hh*4+d4]; float4 qv = qh4[hh*4+d4];
        acc += kv.x*qv.x + kv.y*qv.y + kv.z*qv.z + kv.w*qv.w;
      }
      sc[hh*441+l] = msk ? -1e9f : acc*0.25f;
    }
  }
  __syncthreads();
  int wave = tid>>6, lane = tid&63;
  for (int hh = wave; hh < 8; hh += 4){
    float mx = -3.0e38f;
    for (int l = lane; l < 441; l += 64) mx = fmaxf(mx, sc[hh*441+l]);
    #pragma unroll
    for (int off=32; off; off>>=1) mx = fmaxf(mx, __shfl_xor(mx, off));
    float sum = 0.f;
    for (int l = lane; l < 441; l += 64){
      float e = __expf(sc[hh*441+l] - mx);
      sc[hh*441+l] = e; sum += e;
    }
    #pragma unroll
    for (int off=32; off; off>>=1) sum += __shfl_xor(sum, off);
    if (lane==0) sumsL[hh] = sum;
  }
  __syncthreads();
  for (int hh = wave; hh < 8; hh += 4){
    float a[16];
    #pragma unroll
    for (int d=0; d<16; ++d) a[d]=0.f;
    for (int l = lane; l < 441; l += 64){
      float w = sc[hh*441+l];
      const float4* vv4 = (const float4*)(VV + (size_t)kiL[l]*128 + hh*16);
      #pragma unroll
      for (int d4=0; d4<4; ++d4){
        float4 v = vv4[d4];
        a[d4*4+0]+=w*v.x; a[d4*4+1]+=w*v.y; a[d4*4+2]+=w*v.z; a[d4*4+3]+=w*v.w;
      }
    }
    #pragma unroll
    for (int d=0; d<16; ++d){
      #pragma unroll
      for (int off=32; off; off>>=1) a[d] += __shfl_xor(a[d], off);
    }
    if (lane==0){
      float inv = 1.f/sumsL[hh];
      #pragma unroll
      for (int d=0; d<16; ++d) ctxL[hh*16+d] = a[d]*inv;
    }
  }
  __syncthreads();
  {
    const float4* wp = (const float4*)(WOT + (size_t)c128*128 + kb64);
    float acc = 0.f;
    #pragma unroll
    for (int k4=0;k4<16;++k4){
      float4 w = wp[k4]; int kb = kb64 + k4*4;
      acc += ctxL[kb]*w.x + ctxL[kb+1]*w.y + ctxL[kb+2]*w.z + ctxL[kb+3]*w.w;
    }
    sc[tid] = acc;
  }
  __syncthreads();
  float x1v = 0.f;
  if (tid < 128){
    x1v = qreg + bo[tid] + sc[tid] + sc[tid+128];
    xL[tid] = x1v;
  }
  __syncthreads();
  if (tid < 64){
    float u0 = xL[tid], u1 = xL[tid+64];
    float s = u0+u1, s2 = u0*u0+u1*u1;
    #pragma unroll
    for (int off=32; off; off>>=1){ s += __shfl_xor(s, off); s2 += __shfl_xor(s2, off); }
    if (tid==0){ float mean = s*(1.f/128.f); float var = s2*(1.f/128.f) - mean*mean;
      stat[0]=mean; stat[1]=rsqrtf(var + 1e-5f); }
  }
  __syncthreads();
  if (tid < 128) xL[tid] = (x1v - stat[0])*stat[1]*g1[tid] + b1[tid];
  __syncthreads();
  {
    const float4* wp = (const float4*)(WF1T + (size_t)tid*128);
    float hv = bf1[tid];
    #pragma unroll 8
    for (int k4=0;k4<32;++k4){
      float4 w = wp[k4]; int kb = k4*4;
      hv += xL[kb]*w.x + xL[kb+1]*w.y + xL[kb+2]*w.z + xL[kb+3]*w.w;
    }
    hidL[tid] = fmaxf(hv, 0.f);
  }
  __syncthreads();
  {
    int kb0 = (tid>>7)*128;
    const float4* wp = (const float4*)(WF2T + (size_t)c128*256 + kb0);
    float acc = 0.f;
    #pragma unroll 8
    for (int k4=0;k4<32;++k4){
      float4 w = wp[k4]; int kb = kb0 + k4*4;
      acc += hidL[kb]*w.x + hidL[kb+1]*w.y + hidL[kb+2]*w.z + hidL[kb+3]*w.w;
    }
    sc[tid] = acc;
  }
  __syncthreads();
  float x2v = 0.f;
  if (tid < 128) x2v = xL[tid] + bf2[tid] + sc[tid] + sc[tid+128];
  __syncthreads();
  if (tid < 128) hidL[tid] = x2v;
  __syncthreads();
  if (tid < 64){
    float u0 = hidL[tid], u1 = hidL[tid+64];
    float s = u0+u1, s2 = u0*u0+u1*u1;
    #pragma unroll
    for (int off=32; off; off>>=1){ s += __shfl_xor(s, off); s2 += __shfl_xor(s2, off); }
    if (tid==0){ float mean = s*(1.f/128.f); float var = s2*(1.f/128.f) - mean*mean;
      stat[0]=mean; stat[1]=rsqrtf(var + 1e-5f); }
  }
  __syncthreads();
  if (tid < 128) xL[tid] = (x2v - stat[0])*stat[1]*g2[tid] + b2[tid];   // final x2
  __syncthreads();
  if (tid < 14){
    const float* Wp; float bb;
    if (tid < 2)      { Wp = Wc + tid*128;        bb = bc[tid];      }
    else if (tid < 3) { Wp = Wh;                  bb = bh[0];        }
    else if (tid < 6) { Wp = Wd + (tid-3)*128;    bb = bd[tid-3];    }
    else if (tid < 8) { Wp = Wr + (tid-6)*128;    bb = br[tid-6];    }
    else              { Wp = Whm2 + (tid-8)*128;  bb = bhm2[tid-8];  }
    float acc = bb;
    for (int k=0;k<128;++k) acc += xL[k]*Wp[k];
    dots[tid] = acc;
  }
  __syncthreads();
  if (tid == 0){
    float qpx = (float)(sp/132)+0.5f, qpy = (float)(sp%132)+0.5f;
    float cx = (dots[0]+qpx)*0.64f - 61.44f;
    float cy = (dots[1]+qpy)*0.64f - 42.24f;
    float e0 = expf(dots[3]), e1 = expf(dots[4]), e2 = expf(dots[5]);
    float hgt = dots[2] - e2*0.5f;
    float rot = atanf(dots[6]/(dots[7] + 1e-6f));
    float bestv = -1.f; int bestc = 0;
    #pragma unroll
    for (int m=0;m<6;++m){
      float s = 1.f/(1.f + expf(-dots[8+m]));
      if (s > bestv){ bestv = s; bestc = m; }
    }
    float* o = out + (size_t)n*9;
    o[0]=cx; o[1]=cy; o[2]=hgt; o[3]=e0; o[4]=e1; o[5]=e2; o[6]=rot;
    o[7]=(float)bestc; o[8]=bestv;
  }
}

// ---------------- launcher ----------------
extern "C" void kernel_launch(void* const* d_in, const int* in_sizes, int n_in,
                              void* d_out, int out_size, void* d_ws, size_t ws_size,
                              hipStream_t stream){
  (void)in_sizes; (void)n_in; (void)out_size;
  const float* IN   = (const float*)d_in[0];
  const float* Wsh  = (const float*)d_in[1];
  const float* bsh  = (const float*)d_in[2];
  const float* Whm  = (const float*)d_in[3];
  const float* bhm  = (const float*)d_in[4];
  const float* Wcls = (const float*)d_in[5];
  const float* bcls = (const float*)d_in[6];
  const float* Wp1  = (const float*)d_in[7];
  const float* bp1  = (const float*)d_in[8];
  const float* Wp2  = (const float*)d_in[9];
  const float* bp2  = (const float*)d_in[10];
  const float* Wq   = (const float*)d_in[11];
  const float* bq   = (const float*)d_in[12];
  const float* Wk   = (const float*)d_in[13];
  const float* bk   = (const float*)d_in[14];
  const float* Wv   = (const float*)d_in[15];
  const float* bv   = (const float*)d_in[16];
  const float* Wo   = (const float*)d_in[17];
  const float* bo   = (const float*)d_in[18];
  const float* g1   = (const float*)d_in[19];
  const float* b1   = (const float*)d_in[20];
  const float* g2   = (const float*)d_in[21];
  const float* b2   = (const float*)d_in[22];
  const float* Wf1  = (const float*)d_in[23];
  const float* bf1  = (const float*)d_in[24];
  const float* Wf2  = (const float*)d_in[25];
  const float* bf2  = (const float*)d_in[26];
  const float* Wc   = (const float*)d_in[27];
  const float* bc   = (const float*)d_in[28];
  const float* Wh   = (const float*)d_in[29];
  const float* bh   = (const float*)d_in[30];
  const float* Wd   = (const float*)d_in[31];
  const float* bd   = (const float*)d_in[32];
  const float* Wr   = (const float*)d_in[33];
  const float* br   = (const float*)d_in[34];
  const float* Whm2 = (const float*)d_in[37];
  const float* bhm2 = (const float*)d_in[38];
  float* out = (float*)d_out;
  float* W = (float*)d_ws;

  const size_t N_LFF  = (size_t)HW*128;
  const size_t OFF_LFF  = 0;
  const size_t OFF_PE   = OFF_LFF + N_LFF;         // conv1 partial g1
  const size_t OFF_KK   = OFF_PE + N_LFF;          // conv1 partial g2, then KK
  const size_t OFF_VV   = OFF_KK + N_LFF;          // conv1 partial g3, then VV
  const size_t OFF_WT   = OFF_VV + N_LFF;          // 294912
  const size_t OFF_WHMT = OFF_WT + 294912;         // 6912
  const size_t OFF_HMS  = OFF_WHMT + 6912;         // 152064
  const size_t OFF_VALS = OFF_HMS + 152064;        // 152064
  const size_t OFF_HIST = OFF_VALS + 152064;       // 65536
  const size_t OFF_SCAN = OFF_HIST + 65536;        // 16
  const size_t OFF_CNT  = OFF_SCAN + 16;           // 16
  const size_t OFF_CV   = OFF_CNT + 16;            // CAP
  const size_t OFF_CI   = OFF_CV + CAP;            // CAP
  const size_t OFF_TOPS = OFF_CI + CAP;            // 512
  const size_t OFF_TOPC = OFF_TOPS + 512;          // 512
  const size_t OFF_WQT  = OFF_TOPC + 512;          // 16384
  const size_t OFF_WP2T = OFF_WQT + 16384;         // 16384
  const size_t OFF_WOT  = OFF_WP2T + 16384;        // 16384
  const size_t OFF_WF1T = OFF_WOT + 16384;         // 32768
  const size_t OFF_WF2T = OFF_WF1T + 32768;        // 32768
  const size_t TOTAL    = OFF_WF2T + 32768;
  if (ws_size < TOTAL*sizeof(float)) return;

  // k_wt also zeroes HIST|SCAN|CNT (65568 ints, contiguous at OFF_HIST)
  k_wt    <<<1152, 256, 0, stream>>>(Wsh, Whm, Wq, Wp2, Wo, Wf1, Wf2,
                                     W+OFF_WT, W+OFF_WHMT,
                                     W+OFF_WQT, W+OFF_WP2T, W+OFF_WOT, W+OFF_WF1T, W+OFF_WF2T,
                                     (int*)(W+OFF_HIST));
  k_conv1 <<<dim3(396,4), 256, 0, stream>>>(IN, W+OFF_WT, W+OFF_LFF, W+OFF_PE, W+OFF_KK, W+OFF_VV);
  k_cadd  <<<3168, 256, 0, stream>>>(W+OFF_LFF, W+OFF_PE, W+OFF_KK, W+OFF_VV, bsh);
  k_mid   <<<1188, 256, 0, stream>>>(W+OFF_LFF, Wp1, bp1, Wp2, bp2, Wk, bk, Wv, bv,
                                     W+OFF_KK, W+OFF_VV, W+OFF_WHMT, bhm, W+OFF_HMS);
  k_nms   <<<594,  256, 0, stream>>>(W+OFF_HMS, W+OFF_VALS, (int*)(W+OFF_HIST));
  k_scan  <<<1,   1024, 0, stream>>>((const int*)(W+OFF_HIST), (int*)(W+OFF_SCAN));
  k_collect<<<594, 256, 0, stream>>>(W+OFF_VALS, (const int*)(W+OFF_SCAN),
                                     (int*)(W+OFF_CNT), W+OFF_CV, (int*)(W+OFF_CI));
  k_sort  <<<1,   1024, 0, stream>>>(W+OFF_CV, (const int*)(W+OFF_CI), (const int*)(W+OFF_CNT),
                                     (int*)(W+OFF_TOPS), (int*)(W+OFF_TOPC));
  k_attn  <<<500,  256, 0, stream>>>(W+OFF_KK, W+OFF_VV, W+OFF_LFF,
                                     (const int*)(W+OFF_TOPS), (const int*)(W+OFF_TOPC),
                                     Wcls, bcls, Wp1, bp1, W+OFF_WP2T, bp2, W+OFF_WQT, bq,
                                     W+OFF_WOT, bo, g1, b1, W+OFF_WF1T, bf1, W+OFF_WF2T, bf2, g2, b2,
                                     Wc, bc, Wh, bh, Wd, bd, Wr, br, Whm2, bhm2, out);
}

// Round 12
// 543.122 us; speedup vs baseline: 1.3453x; 1.0740x over previous
//
#include <hip/hip_runtime.h>
#include <math.h>
#include <float.h>

#define XG 192
#define YG 132
#define HW 25344           // 192*132
#define NCLS 6
#define NPROP 500
#define LWIN 441
#define CAP 2048           // candidate cap for top-k sort (one-level select)

typedef unsigned short ushort_t;
typedef __attribute__((ext_vector_type(8))) short bf8v;   // 8 bf16 (4 VGPRs)
typedef __attribute__((ext_vector_type(4))) float f4v;    // 4 fp32 acc

static __device__ __forceinline__ int imin(int a,int b){return a<b?a:b;}
static __device__ __forceinline__ int imax(int a,int b){return a>b?a:b;}

// async global->LDS, 16B per lane; LDS dest is wave-uniform base + lane*16
__device__ __forceinline__ void gl_lds16(const float* gp, float* lp){
  __builtin_amdgcn_global_load_lds(
      (const __attribute__((address_space(1))) unsigned int*)gp,
      (__attribute__((address_space(3))) unsigned int*)lp,
      16, 0, 0);
}
__device__ __forceinline__ void gl_lds16u(const ushort_t* gp, ushort_t* lp){
  __builtin_amdgcn_global_load_lds(
      (const __attribute__((address_space(1))) unsigned int*)gp,
      (__attribute__((address_space(3))) unsigned int*)lp,
      16, 0, 0);
}

__device__ __forceinline__ ushort_t f2bf(float x){          // RNE truncate to bf16
  unsigned u = __float_as_uint(x);
  return (ushort_t)((u + 0x7FFFu + ((u>>16)&1u)) >> 16);
}
__device__ __forceinline__ float bf2f(ushort_t h){
  return __uint_as_float(((unsigned)h)<<16);
}

// ---------------- weight prep: bf16-split conv1 weights + W6 + attn transposes + zeroing ----------
// BQs[(tap*8+chunk)*5120 + n*40 + kl] = split_s( Ws[n][chunk*32+kl][tap] ), kl<32; 32..39 pad unused
__global__ __launch_bounds__(256) void k_wt(const float* __restrict__ Ws,
                                            const float* __restrict__ Whm,
                                            const float* __restrict__ Wq,
                                            const float* __restrict__ Wp2,
                                            const float* __restrict__ Wo,
                                            const float* __restrict__ Wf1,
                                            const float* __restrict__ Wf2,
                                            float* __restrict__ W6,
                                            float* __restrict__ WQT,
                                            float* __restrict__ WP2T,
                                            float* __restrict__ WOT,
                                            float* __restrict__ WF1T,
                                            float* __restrict__ WF2T,
                                            ushort_t* __restrict__ BQ0,
                                            ushort_t* __restrict__ BQ1,
                                            ushort_t* __restrict__ BQ2,
                                            int* __restrict__ Z){
  int t = blockIdx.x*256 + threadIdx.x;
  if (t < 294912){
    int kl = t & 31;
    int rest = t >> 5;
    int n = rest & 127;
    int tc = rest >> 7;            // tap*8 + chunk
    int tap = tc >> 3, chunk = tc & 7;
    int c = chunk*32 + kl;
    float v = Ws[(size_t)n*2304 + c*9 + tap];
    ushort_t h0 = f2bf(v);
    float r1 = v - bf2f(h0);
    ushort_t h1 = f2bf(r1);
    float r2 = r1 - bf2f(h1);
    ushort_t h2 = f2bf(r2);
    size_t dst = (size_t)tc*5120 + n*40 + kl;
    BQ0[dst] = h0; BQ1[dst] = h1; BQ2[dst] = h2;
  }
  if (t < 6912){
    int c = t & 127, row = t >> 7;      // row = cls*9+tap, 54 rows
    int cls = row / 9, tap = row % 9;
    W6[t] = Whm[(size_t)cls*1152 + c*9 + tap];
  }
  if (t < 16384){
    int k = t & 127, c = t >> 7;
    WQT[t]  = Wq [(size_t)k*128 + c];
    WP2T[t] = Wp2[(size_t)k*128 + c];
    WOT[t]  = Wo [(size_t)k*128 + c];
  }
  if (t < 32768){
    { int k = t & 127, o = t >> 7;  WF1T[t] = Wf1[(size_t)k*256 + o]; }
    { int k = t & 255, c = t >> 8;  WF2T[t] = Wf2[(size_t)k*128 + c]; }
  }
  if (t < 65568) Z[t] = 0;              // HIST 65536 | SCAN 16 | CNT 16
}

// ---------------- conv1 v10: split-bf16 MFMA implicit GEMM ----------------
// grid 396 = 3 i-strips(64) x 132 cols. block 256 = 4 waves.
// M=64, N=128, K=2304 reordered [tap][ch]; per k-step one 16x16x32 MFMA-K.
// Wave w: ntiles {2w,2w+1}, all 4 M-frags. 6 MFMA terms/tile-pair (split-bf16, err ~1e-7).
// Writes LFF directly with bias+relu (k_cadd eliminated).
__global__ __launch_bounds__(256, 3) void k_conv1(const float* __restrict__ IN,
                                                  const ushort_t* __restrict__ BQ0,
                                                  const ushort_t* __restrict__ BQ1,
                                                  const ushort_t* __restrict__ BQ2,
                                                  const float* __restrict__ bias,
                                                  float* __restrict__ LFF){
  const int b  = blockIdx.x;
  const int i0 = (b % 3) * 64;
  const int j  = b / 3;
  const int tid = threadIdx.x;
  const int w    = tid >> 6;
  const int lane = tid & 63;
  const int l15  = lane & 15, quad = lane >> 4;
  __shared__ __align__(16) ushort_t SM[23280];   // A: 3x2640 | B: 3x5120 (46560 B)
  ushort_t* As0 = SM;                 // [px 66][chpad 40]
  ushort_t* As1 = SM + 2640;
  ushort_t* As2 = SM + 5280;
  ushort_t* Bs0 = SM + 7920;          // [n 128][chpad 40]
  ushort_t* Bs1 = SM + 13040;
  ushort_t* Bs2 = SM + 18160;
  f4v acc[4][2];
  #pragma unroll
  for (int mq=0;mq<4;++mq)
    #pragma unroll
    for (int nt=0;nt<2;++nt) acc[mq][nt] = (f4v){0.f,0.f,0.f,0.f};

  for (int chunk=0; chunk<8; ++chunk){
    for (int kw=0; kw<3; ++kw){
      __syncthreads();                 // prior tap's reads of As/Bs done
      // ---- stage A row (gj = j-1+kw), 32 ch, convert to 3 bf16 splits ----
      {
        int gj = j - 1 + kw;
        bool jok = (unsigned)gj < 132u;
        for (int e = tid; e < 2112; e += 256){
          int c = e / 66, ii = e - c*66;
          int gi = i0 - 1 + ii;
          float v = 0.f;
          if (jok && (unsigned)gi < 192u)
            v = IN[(size_t)(chunk*32 + c)*25344 + gj*192 + gi];
          ushort_t h0 = f2bf(v);
          float r1 = v - bf2f(h0);
          ushort_t h1 = f2bf(r1);
          float r2 = r1 - bf2f(h1);
          ushort_t h2 = f2bf(r2);
          int a = ii*40 + c;
          As0[a] = h0; As1[a] = h1; As2[a] = h2;
        }
      }
      for (int kh=0; kh<3; ++kh){
        if (kh > 0) __syncthreads();   // prior mfma's Bs reads done
        // ---- stage B for tap = kh*3+kw (async, padded rows preserved) ----
        {
          int tc = (kh*3 + kw)*8 + chunk;
          const ushort_t* s0 = BQ0 + (size_t)tc*5120;
          const ushort_t* s1 = BQ1 + (size_t)tc*5120;
          const ushort_t* s2 = BQ2 + (size_t)tc*5120;
          gl_lds16u(s0 + (size_t)tid*8,       Bs0 + (size_t)(w*64)*8);
          gl_lds16u(s0 + (size_t)(256+tid)*8, Bs0 + (size_t)(256 + w*64)*8);
          gl_lds16u(s1 + (size_t)tid*8,       Bs1 + (size_t)(w*64)*8);
          gl_lds16u(s1 + (size_t)(256+tid)*8, Bs1 + (size_t)(256 + w*64)*8);
          gl_lds16u(s2 + (size_t)tid*8,       Bs2 + (size_t)(w*64)*8);
          gl_lds16u(s2 + (size_t)(256+tid)*8, Bs2 + (size_t)(256 + w*64)*8);
          if (tid < 128){
            gl_lds16u(s0 + (size_t)(512+tid)*8, Bs0 + (size_t)(512 + w*64)*8);
            gl_lds16u(s1 + (size_t)(512+tid)*8, Bs1 + (size_t)(512 + w*64)*8);
            gl_lds16u(s2 + (size_t)(512+tid)*8, Bs2 + (size_t)(512 + w*64)*8);
          }
        }
        __syncthreads();               // staging visible (A for kh==0, B always)
        // ---- 6-term split-bf16 MFMA ----
        bf8v A0[4], A1[4], A2[4];
        #pragma unroll
        for (int mq=0; mq<4; ++mq){
          int off = (mq*16 + l15 + kh)*40 + quad*8;
          A0[mq] = *(const bf8v*)&As0[off];
          A1[mq] = *(const bf8v*)&As1[off];
          A2[mq] = *(const bf8v*)&As2[off];
        }
        bf8v B0[2], B1[2], B2[2];
        #pragma unroll
        for (int ntl=0; ntl<2; ++ntl){
          int off = ((w*2+ntl)*16 + l15)*40 + quad*8;
          B0[ntl] = *(const bf8v*)&Bs0[off];
          B1[ntl] = *(const bf8v*)&Bs1[off];
          B2[ntl] = *(const bf8v*)&Bs2[off];
        }
        #pragma unroll
        for (int mq=0;mq<4;++mq){
          #pragma unroll
          for (int ntl=0;ntl<2;++ntl){
            f4v c = acc[mq][ntl];
            c = __builtin_amdgcn_mfma_f32_16x16x32_bf16(A0[mq], B0[ntl], c, 0,0,0);
            c = __builtin_amdgcn_mfma_f32_16x16x32_bf16(A0[mq], B1[ntl], c, 0,0,0);
            c = __builtin_amdgcn_mfma_f32_16x16x32_bf16(A1[mq], B0[ntl], c, 0,0,0);
            c = __builtin_amdgcn_mfma_f32_16x16x32_bf16(A0[mq], B2[ntl], c, 0,0,0);
            c = __builtin_amdgcn_mfma_f32_16x16x32_bf16(A1[mq], B1[ntl], c, 0,0,0);
            c = __builtin_amdgcn_mfma_f32_16x16x32_bf16(A2[mq], B0[ntl], c, 0,0,0);
            acc[mq][ntl] = c;
          }
        }
      }
    }
  }
  // ---- epilogue: LDS transpose -> bias+relu -> coalesced stores ----
  __syncthreads();
  float* Cs = (float*)SM;              // 64 x 128 fp32 = 32768 B <= 46560
  #pragma unroll
  for (int mq=0;mq<4;++mq)
    #pragma unroll
    for (int ntl=0;ntl<2;++ntl)
      #pragma unroll
      for (int r=0;r<4;++r){
        int m = mq*16 + quad*4 + r;          // C/D: row = quad*4+reg
        int oc = (w*2+ntl)*16 + l15;         //      col = lane&15
        Cs[m*128 + oc] = acc[mq][ntl][r];
      }
  __syncthreads();
  for (int e = tid; e < 2048; e += 256){
    int m = e >> 5, ocq = e & 31;
    float4 v = *(float4*)&Cs[m*128 + ocq*4];
    float4 bs = *(const float4*)&bias[ocq*4];
    v.x = fmaxf(v.x + bs.x, 0.f);
    v.y = fmaxf(v.y + bs.y, 0.f);
    v.z = fmaxf(v.z + bs.z, 0.f);
    v.w = fmaxf(v.w + bs.w, 0.f);
    int p = (i0 + m)*132 + j;
    *(float4*)&LFF[(size_t)p*128 + ocq*4] = v;
  }
}

// ---------------- fused (kkvv | conv2) ; both weight paths LDS-staged (R10/R11-proven) ----------
__global__ __launch_bounds__(256) void k_mid(const float* __restrict__ LFF,
                                             const float* __restrict__ W1, const float* __restrict__ b1,
                                             const float* __restrict__ W2, const float* __restrict__ b2,
                                             const float* __restrict__ Wk, const float* __restrict__ bk,
                                             const float* __restrict__ Wv, const float* __restrict__ bv,
                                             float* __restrict__ KK, float* __restrict__ VV,
                                             const float* __restrict__ W6, const float* __restrict__ bhm,
                                             float* __restrict__ HMS){
  __shared__ float smem[12288];   // kkvv: hs 4096 | sf 4096 | wbuf 4096 (48KB)
  const int tid = threadIdx.x;
  const int wv4 = tid >> 6;
  if (blockIdx.x < 792){
    float* hs   = smem;
    float* sf   = smem + 4096;
    float* wbuf = smem + 8192;
    const int p0 = blockIdx.x*32;
    for (int e=tid; e<4096; e+=256){
      int k = e>>5, px = e&31;
      int p = p0+px;
      float bx = (float)(p/132)+0.5f, by = (float)(p%132)+0.5f;
      hs[k*32+px] = fmaxf(bx*W1[k] + by*W1[128+k] + b1[k], 0.f);
    }
    for (int e=tid; e<4096; e+=256){
      int px = e>>7, k = e&127;
      sf[k*32+px] = LFF[(size_t)(p0+px)*128 + k];
    }
    const int pxg = tid & 15, ocg = tid >> 4;   // 16 x 16
    const int px0 = pxg*2, oc0 = ocg*8;
    float accA[2][8];
    #pragma unroll
    for (int r=0;r<2;++r)
      #pragma unroll
      for (int u=0;u<8;++u) accA[r][u]=0.f;
    for (int c0=0; c0<128; c0+=32){
      __syncthreads();
      const float* wsrc = W2 + (size_t)c0*128;
      #pragma unroll
      for (int r=0;r<4;++r)
        gl_lds16(wsrc + (size_t)(r*256+tid)*4, wbuf + (size_t)(r*256+wv4*64)*4);
      __syncthreads();
      #pragma unroll 2
      for (int k=0;k<32;++k){
        float a0 = hs[(c0+k)*32+px0], a1 = hs[(c0+k)*32+px0+1];
        const float4* w = (const float4*)(wbuf + (size_t)k*128 + oc0);
        float4 w0 = w[0], w1 = w[1];
        accA[0][0]+=a0*w0.x; accA[0][1]+=a0*w0.y; accA[0][2]+=a0*w0.z; accA[0][3]+=a0*w0.w;
        accA[0][4]+=a0*w1.x; accA[0][5]+=a0*w1.y; accA[0][6]+=a0*w1.z; accA[0][7]+=a0*w1.w;
        accA[1][0]+=a1*w0.x; accA[1][1]+=a1*w0.y; accA[1][2]+=a1*w0.z; accA[1][3]+=a1*w0.w;
        accA[1][4]+=a1*w1.x; accA[1][5]+=a1*w1.y; accA[1][6]+=a1*w1.z; accA[1][7]+=a1*w1.w;
      }
    }
    __syncthreads();
    #pragma unroll
    for (int u=0;u<8;++u){
      float bb = b2[oc0+u];
      hs[(oc0+u)*32+px0]   = sf[(oc0+u)*32+px0]   + accA[0][u] + bb;
      hs[(oc0+u)*32+px0+1] = sf[(oc0+u)*32+px0+1] + accA[1][u] + bb;
    }
    float accK[2][8], accV[2][8];
    #pragma unroll
    for (int u=0;u<8;++u){
      float k0 = bk[oc0+u], v0 = bv[oc0+u];
      accK[0][u]=k0; accK[1][u]=k0; accV[0][u]=v0; accV[1][u]=v0;
    }
    for (int c0=0; c0<128; c0+=16){
      __syncthreads();
      #pragma unroll
      for (int r=0;r<2;++r){
        gl_lds16(Wk + (size_t)c0*128 + (size_t)(r*256+tid)*4, wbuf + (size_t)(r*256+wv4*64)*4);
        gl_lds16(Wv + (size_t)c0*128 + (size_t)(r*256+tid)*4, wbuf + 2048 + (size_t)(r*256+wv4*64)*4);
      }
      __syncthreads();
      #pragma unroll 2
      for (int k=0;k<16;++k){
        int kk = c0+k;
        float s0 = hs[kk*32+px0], s1 = hs[kk*32+px0+1];
        float f0 = sf[kk*32+px0], f1 = sf[kk*32+px0+1];
        const float4* wkp = (const float4*)(wbuf + (size_t)k*128 + oc0);
        const float4* wvp = (const float4*)(wbuf + 2048 + (size_t)k*128 + oc0);
        float4 k0v = wkp[0], k1v = wkp[1], v0v = wvp[0], v1v = wvp[1];
        accK[0][0]+=s0*k0v.x; accK[0][1]+=s0*k0v.y; accK[0][2]+=s0*k0v.z; accK[0][3]+=s0*k0v.w;
        accK[0][4]+=s0*k1v.x; accK[0][5]+=s0*k1v.y; accK[0][6]+=s0*k1v.z; accK[0][7]+=s0*k1v.w;
        accK[1][0]+=s1*k0v.x; accK[1][1]+=s1*k0v.y; accK[1][2]+=s1*k0v.z; accK[1][3]+=s1*k0v.w;
        accK[1][4]+=s1*k1v.x; accK[1][5]+=s1*k1v.y; accK[1][6]+=s1*k1v.z; accK[1][7]+=s1*k1v.w;
        accV[0][0]+=f0*v0v.x; accV[0][1]+=f0*v0v.y; accV[0][2]+=f0*v0v.z; accV[0][3]+=f0*v0v.w;
        accV[0][4]+=f0*v1v.x; accV[0][5]+=f0*v1v.y; accV[0][6]+=f0*v1v.z; accV[0][7]+=f0*v1v.w;
        accV[1][0]+=f1*v0v.x; accV[1][1]+=f1*v0v.y; accV[1][2]+=f1*v0v.z; accV[1][3]+=f1*v0v.w;
        accV[1][4]+=f1*v1v.x; accV[1][5]+=f1*v1v.y; accV[1][6]+=f1*v1v.z; accV[1][7]+=f1*v1v.w;
      }
    }
    #pragma unroll
    for (int r=0;r<2;++r){
      int p = p0+px0+r;
      float4* oK = (float4*)(KK + (size_t)p*128 + oc0);
      float4* oV = (float4*)(VV + (size_t)p*128 + oc0);
      float4 t0, t1;
      t0.x=accK[r][0]; t0.y=accK[r][1]; t0.z=accK[r][2]; t0.w=accK[r][3];
      t1.x=accK[r][4]; t1.y=accK[r][5]; t1.z=accK[r][6]; t1.w=accK[r][7];
      oK[0]=t0; oK[1]=t1;
      t0.x=accV[r][0]; t0.y=accV[r][1]; t0.z=accV[r][2]; t0.w=accV[r][3];
      t1.x=accV[r][4]; t1.y=accV[r][5]; t1.z=accV[r][6]; t1.w=accV[r][7];
      oV[0]=t0; oV[1]=t1;
    }
  } else {
    float* w6s = smem;          // 6912 floats
    float* red = smem + 8192;
    for (int e=tid; e<6912; e+=256) w6s[e] = W6[e];
    __syncthreads();
    int lane = tid & 63, wave = tid >> 6;
    int p = (blockIdx.x - 792)*64 + lane;        // 396*64 = 25344
    int i = p/132, j = p%132;
    float acc[6] = {0.f,0.f,0.f,0.f,0.f,0.f};
    int cbase = wave*32;
    #pragma unroll
    for (int kh=0; kh<3; ++kh){
      int gi = i+kh-1;
      if ((unsigned)gi >= 192u) continue;
      #pragma unroll
      for (int kw=0; kw<3; ++kw){
        int gj = j+kw-1;
        if ((unsigned)gj >= 132u) continue;
        const float* row = LFF + (size_t)(gi*132+gj)*128 + cbase;
        int tap = kh*3+kw;
        #pragma unroll
        for (int cq=0; cq<8; ++cq){
          float4 v = *(const float4*)(row + cq*4);
          #pragma unroll
          for (int cls=0; cls<6; ++cls){
            float4 wv = *(const float4*)(w6s + (size_t)(cls*9+tap)*128 + cbase + cq*4);
            acc[cls] += v.x*wv.x + v.y*wv.y + v.z*wv.z + v.w*wv.w;
          }
        }
      }
    }
    __syncthreads();
    #pragma unroll
    for (int c=0;c<6;++c) red[(wave*6+c)*64 + lane] = acc[c];
    __syncthreads();
    if (wave==0){
      #pragma unroll
      for (int c=0;c<6;++c){
        float s = red[c*64+lane] + red[(6+c)*64+lane] + red[(12+c)*64+lane] + red[(18+c)*64+lane] + bhm[c];
        HMS[(size_t)c*HW + p] = 1.f/(1.f+expf(-s));
      }
    }
  }
}

// ---------------- NMS + threshold + 16-bit histogram ----------------
__global__ __launch_bounds__(256) void k_nms(const float* __restrict__ HMS,
                                             float* __restrict__ VALS,
                                             int* __restrict__ HIST){
  int t = blockIdx.x*256 + threadIdx.x;   // 594*256 = 152064
  int c = t / HW, p = t % HW;
  int i = p/132, j = p%132;
  float h = HMS[t];
  float v;
  if (c < 3){
    v = 0.f;
    if (i>=1 && i<=190 && j>=1 && j<=130){
      float m = -1e30f;
      #pragma unroll
      for (int di=-1;di<=1;++di)
        #pragma unroll
        for (int dj=-1;dj<=1;++dj)
          m = fmaxf(m, HMS[(size_t)c*HW + (i+di)*132 + (j+dj)]);
      if (h == m) v = h;
    }
  } else v = h;
  if (!(v > 0.01f)) v = 0.f;
  VALS[t] = v;
  if (v > 0.f) atomicAdd(HIST + (__float_as_uint(v)>>16), 1);
}

// ---------------- level-1 scan: parallel suffix scan (R9-proven) ----------------
__global__ __launch_bounds__(1024) void k_scan(const int* __restrict__ HIST, int* __restrict__ SCAN){
  __shared__ int part[1024];
  __shared__ int gsel;
  int t = threadIdx.x;
  int s = 0, base = t*64;
  for (int u=0;u<64;++u) s += HIST[base+u];
  part[t] = s;
  __syncthreads();
  for (int off=1; off<1024; off<<=1){
    int add = (t+off < 1024) ? part[t+off] : 0;
    __syncthreads();
    part[t] += add;
    __syncthreads();
  }
  int total = part[0];
  int mineI = part[t];
  int nextI = (t < 1023) ? part[t+1] : 0;
  if (mineI >= NPROP && nextI < NPROP) gsel = t;
  if (t == 0 && total < NPROP) gsel = -1;
  __syncthreads();
  int g = gsel;
  if (g < 0){
    if (t==0){ SCAN[0] = 0; SCAN[1] = total; }
    return;
  }
  int cumG = (g < 1023) ? part[g+1] : 0;
  if (t < 64){
    int x = HIST[g*64 + t];
    #pragma unroll
    for (int off=1; off<64; off<<=1){
      int y = __shfl_down(x, off);
      x += (t + off < 64) ? y : 0;
    }
    int Snext = __shfl_down(x, 1);
    int incl  = cumG + x;
    int nextc = (t==63) ? cumG : cumG + Snext;
    if (incl >= NPROP && nextc < NPROP){
      SCAN[0] = g*64 + t;
      SCAN[1] = nextc;
    }
  }
}

// ---------------- collect candidates with bin >= bstar ----------------
__global__ __launch_bounds__(256) void k_collect(const float* __restrict__ VALS,
                                                 const int* __restrict__ SCAN,
                                                 int* __restrict__ CNT,
                                                 float* __restrict__ CV, int* __restrict__ CI){
  int t = blockIdx.x*256 + threadIdx.x;   // 594*256 = 152064
  float v = VALS[t];
  int bstar = SCAN[0];
  if (v > 0.f && (int)(__float_as_uint(v)>>16) >= bstar){
    int pos = atomicAdd(CNT, 1);
    if (pos < CAP){ CV[pos] = v; CI[pos] = t; }
  }
}

// ---------------- bitonic sort candidates (2048), take top-500 ----------------
__global__ __launch_bounds__(1024) void k_sort(const float* __restrict__ CV, const int* __restrict__ CI,
                                               const int* __restrict__ CNT,
                                               int* __restrict__ TOPS, int* __restrict__ TOPC){
  __shared__ float sv[CAP];
  __shared__ int   si[CAP];
  int tid = threadIdx.x;
  int M = imin(CNT[0], CAP);
  for (int i=tid; i<CAP; i+=1024){
    if (i < M){ sv[i] = CV[i]; si[i] = CI[i]; }
    else      { sv[i] = -1.f;  si[i] = 0x7fffffff; }
  }
  __syncthreads();
  for (int k=2; k<=CAP; k<<=1){
    for (int j=k>>1; j>0; j>>=1){
      for (int i=tid; i<CAP; i+=1024){
        int p = i ^ j;
        if (p > i){
          bool up = ((i & k) == 0);
          float va = sv[i], vb = sv[p];
          int ia = si[i], ib = si[p];
          bool aFirst = (va > vb) || (va == vb && ia < ib);
          bool bFirst = (vb > va) || (vb == va && ib < ia);
          bool doswap = up ? bFirst : aFirst;
          if (doswap){ sv[i]=vb; sv[p]=va; si[i]=ib; si[p]=ia; }
        }
      }
      __syncthreads();
    }
  }
  for (int t=tid; t<NPROP; t+=1024){
    int idx = imin(si[t], NCLS*HW - 1);
    TOPC[t] = idx / HW;
    TOPS[t] = idx % HW;
  }
}

// ---------------- fused qbuild + attention + LN/FFN/LN + heads + decode (R11-proven) ----------
__global__ __launch_bounds__(256) void k_attn(const float* __restrict__ KK, const float* __restrict__ VV,
                                              const float* __restrict__ LFF,
                                              const int* __restrict__ TOPS, const int* __restrict__ TOPC,
                                              const float* __restrict__ Wcls, const float* __restrict__ bcls,
                                              const float* __restrict__ pW1, const float* __restrict__ pb1,
                                              const float* __restrict__ WP2T, const float* __restrict__ pb2,
                                              const float* __restrict__ WQT, const float* __restrict__ bq,
                                              const float* __restrict__ WOT, const float* __restrict__ bo,
                                              const float* __restrict__ g1, const float* __restrict__ b1,
                                              const float* __restrict__ WF1T, const float* __restrict__ bf1,
                                              const float* __restrict__ WF2T, const float* __restrict__ bf2,
                                              const float* __restrict__ g2, const float* __restrict__ b2,
                                              const float* __restrict__ Wc, const float* __restrict__ bc,
                                              const float* __restrict__ Wh, const float* __restrict__ bh,
                                              const float* __restrict__ Wd, const float* __restrict__ bd,
                                              const float* __restrict__ Wr, const float* __restrict__ br,
                                              const float* __restrict__ Whm2, const float* __restrict__ bhm2,
                                              float* __restrict__ out){
  int n = blockIdx.x, tid = threadIdx.x;
  __shared__ __align__(16) float qhL[128];
  __shared__ float sc[8*441];
  __shared__ int   kiL[441];
  __shared__ __align__(16) float ctxL[128];
  __shared__ float xL[128];
  __shared__ float hidL[256];
  __shared__ float sumsL[8];
  __shared__ float stat[2];
  __shared__ float dots[16];
  int sp = TOPS[n];
  int cls = TOPC[n];
  const int kb64 = (tid>>7)*64, c128 = tid&127;
  float qreg = 0.f;
  if (tid < 128){
    float qx = (float)(sp/132)+0.5f, qy = (float)(sp%132)+0.5f;
    ctxL[tid] = fmaxf(qx*pW1[tid] + qy*pW1[128+tid] + pb1[tid], 0.f);
    qreg = LFF[(size_t)sp*128+tid] + Wcls[tid*6+cls] + bcls[tid];
  }
  __syncthreads();
  {
    const float4* wp = (const float4*)(WP2T + (size_t)c128*128 + kb64);
    float pe = 0.f;
    #pragma unroll
    for (int k4=0;k4<16;++k4){
      float4 w = wp[k4]; int kb = kb64 + k4*4;
      pe += ctxL[kb]*w.x + ctxL[kb+1]*w.y + ctxL[kb+2]*w.z + ctxL[kb+3]*w.w;
    }
    sc[tid] = pe;
  }
  __syncthreads();
  if (tid < 128) xL[tid] = qreg + pb2[tid] + sc[tid] + sc[tid+128];
  __syncthreads();
  {
    const float4* wp = (const float4*)(WQT + (size_t)c128*128 + kb64);
    float qh = 0.f;
    #pragma unroll
    for (int k4=0;k4<16;++k4){
      float4 w = wp[k4]; int kb = kb64 + k4*4;
      qh += xL[kb]*w.x + xL[kb+1]*w.y + xL[kb+2]*w.z + xL[kb+3]*w.w;
    }
    sc[tid] = qh;
  }
  __syncthreads();
  if (tid < 128) qhL[tid] = bq[tid] + sc[tid] + sc[tid+128];
  __syncthreads();
  int spx = sp/192, spy = sp%132;       // faithful to ref's //X_GRID, %Y_GRID
  for (int l = tid; l < 441; l += 256){
    int a = l/21, bb = l%21;
    int kidx = (spx + a - 10)*192 + (spy + bb - 10);
    bool msk = (kidx < 0) || (kidx >= HW);
    int kc = imin(imax(kidx,0), HW-1);
    kiL[l] = kc;
    const float4* kk4 = (const float4*)(KK + (size_t)kc*128);
    const float4* qh4 = (const float4*)qhL;
    #pragma unroll
    for (int hh=0; hh<8; ++hh){
      float acc = 0.f;
      #pragma unroll
      for (int d4=0; d4<4; ++d4){
        float4 kv = kk4[hh*4+d4]; float4 qv = qh4[hh*4+d4];
        acc += kv.x*qv.x + kv.y*qv.y + kv.z*qv.z + kv.w*qv.w;
      }
      sc[hh*441+l] = msk ? -1e9f : acc*0.25f;
    }
  }
  __syncthreads();
  int wave = tid>>6, lane = tid&63;
  for (int hh = wave; hh < 8; hh += 4){
    float mx = -3.0e38f;
    for (int l = lane; l < 441; l += 64) mx = fmaxf(mx, sc[hh*441+l]);
    #pragma unroll
    for (int off=32; off; off>>=1) mx = fmaxf(mx, __shfl_xor(mx, off));
    float sum = 0.f;
    for (int l = lane; l < 441; l += 64){
      float e = __expf(sc[hh*441+l] - mx);
      sc[hh*441+l] = e; sum += e;
    }
    #pragma unroll
    for (int off=32; off; off>>=1) sum += __shfl_xor(sum, off);
    if (lane==0) sumsL[hh] = sum;
  }
  __syncthreads();
  for (int hh = wave; hh < 8; hh += 4){
    float a[16];
    #pragma unroll
    for (int d=0; d<16; ++d) a[d]=0.f;
    for (int l = lane; l < 441; l += 64){
      float w = sc[hh*441+l];
      const float4* vv4 = (const float4*)(VV + (size_t)kiL[l]*128 + hh*16);
      #pragma unroll
      for (int d4=0; d4<4; ++d4){
        float4 v = vv4[d4];
        a[d4*4+0]+=w*v.x; a[d4*4+1]+=w*v.y; a[d4*4+2]+=w*v.z; a[d4*4+3]+=w*v.w;
      }
    }
    #pragma unroll
    for (int d=0; d<16; ++d){
      #pragma unroll
      for (int off=32; off; off>>=1) a[d] += __shfl_xor(a[d], off);
    }
    if (lane==0){
      float inv = 1.f/sumsL[hh];
      #pragma unroll
      for (int d=0; d<16; ++d) ctxL[hh*16+d] = a[d]*inv;
    }
  }
  __syncthreads();
  {
    const float4* wp = (const float4*)(WOT + (size_t)c128*128 + kb64);
    float acc = 0.f;
    #pragma unroll
    for (int k4=0;k4<16;++k4){
      float4 w = wp[k4]; int kb = kb64 + k4*4;
      acc += ctxL[kb]*w.x + ctxL[kb+1]*w.y + ctxL[kb+2]*w.z + ctxL[kb+3]*w.w;
    }
    sc[tid] = acc;
  }
  __syncthreads();
  float x1v = 0.f;
  if (tid < 128){
    x1v = qreg + bo[tid] + sc[tid] + sc[tid+128];
    xL[tid] = x1v;
  }
  __syncthreads();
  if (tid < 64){
    float u0 = xL[tid], u1 = xL[tid+64];
    float s = u0+u1, s2 = u0*u0+u1*u1;
    #pragma unroll
    for (int off=32; off; off>>=1){ s += __shfl_xor(s, off); s2 += __shfl_xor(s2, off); }
    if (tid==0){ float mean = s*(1.f/128.f); float var = s2*(1.f/128.f) - mean*mean;
      stat[0]=mean; stat[1]=rsqrtf(var + 1e-5f); }
  }
  __syncthreads();
  if (tid < 128) xL[tid] = (x1v - stat[0])*stat[1]*g1[tid] + b1[tid];
  __syncthreads();
  {
    const float4* wp = (const float4*)(WF1T + (size_t)tid*128);
    float hv = bf1[tid];
    #pragma unroll 8
    for (int k4=0;k4<32;++k4){
      float4 w = wp[k4]; int kb = k4*4;
      hv += xL[kb]*w.x + xL[kb+1]*w.y + xL[kb+2]*w.z + xL[kb+3]*w.w;
    }
    hidL[tid] = fmaxf(hv, 0.f);
  }
  __syncthreads();
  {
    int kb0 = (tid>>7)*128;
    const float4* wp = (const float4*)(WF2T + (size_t)c128*256 + kb0);
    float acc = 0.f;
    #pragma unroll 8
    for (int k4=0;k4<32;++k4){
      float4 w = wp[k4]; int kb = kb0 + k4*4;
      acc += hidL[kb]*w.x + hidL[kb+1]*w.y + hidL[kb+2]*w.z + hidL[kb+3]*w.w;
    }
    sc[tid] = acc;
  }
  __syncthreads();
  float x2v = 0.f;
  if (tid < 128) x2v = xL[tid] + bf2[tid] + sc[tid] + sc[tid+128];
  __syncthreads();
  if (tid < 128) hidL[tid] = x2v;
  __syncthreads();
  if (tid < 64){
    float u0 = hidL[tid], u1 = hidL[tid+64];
    float s = u0+u1, s2 = u0*u0+u1*u1;
    #pragma unroll
    for (int off=32; off; off>>=1){ s += __shfl_xor(s, off); s2 += __shfl_xor(s2, off); }
    if (tid==0){ float mean = s*(1.f/128.f); float var = s2*(1.f/128.f) - mean*mean;
      stat[0]=mean; stat[1]=rsqrtf(var + 1e-5f); }
  }
  __syncthreads();
  if (tid < 128) xL[tid] = (x2v - stat[0])*stat[1]*g2[tid] + b2[tid];   // final x2
  __syncthreads();
  if (tid < 14){
    const float* Wp; float bb;
    if (tid < 2)      { Wp = Wc + tid*128;        bb = bc[tid];      }
    else if (tid < 3) { Wp = Wh;                  bb = bh[0];        }
    else if (tid < 6) { Wp = Wd + (tid-3)*128;    bb = bd[tid-3];    }
    else if (tid < 8) { Wp = Wr + (tid-6)*128;    bb = br[tid-6];    }
    else              { Wp = Whm2 + (tid-8)*128;  bb = bhm2[tid-8];  }
    float acc = bb;
    for (int k=0;k<128;++k) acc += xL[k]*Wp[k];
    dots[tid] = acc;
  }
  __syncthreads();
  if (tid == 0){
    float qpx = (float)(sp/132)+0.5f, qpy = (float)(sp%132)+0.5f;
    float cx = (dots[0]+qpx)*0.64f - 61.44f;
    float cy = (dots[1]+qpy)*0.64f - 42.24f;
    float e0 = expf(dots[3]), e1 = expf(dots[4]), e2 = expf(dots[5]);
    float hgt = dots[2] - e2*0.5f;
    float rot = atanf(dots[6]/(dots[7] + 1e-6f));
    float bestv = -1.f; int bestc = 0;
    #pragma unroll
    for (int m=0;m<6;++m){
      float s = 1.f/(1.f + expf(-dots[8+m]));
      if (s > bestv){ bestv = s; bestc = m; }
    }
    float* o = out + (size_t)n*9;
    o[0]=cx; o[1]=cy; o[2]=hgt; o[3]=e0; o[4]=e1; o[5]=e2; o[6]=rot;
    o[7]=(float)bestc; o[8]=bestv;
  }
}

// ---------------- launcher ----------------
extern "C" void kernel_launch(void* const* d_in, const int* in_sizes, int n_in,
                              void* d_out, int out_size, void* d_ws, size_t ws_size,
                              hipStream_t stream){
  (void)in_sizes; (void)n_in; (void)out_size;
  const float* IN   = (const float*)d_in[0];
  const float* Wsh  = (const float*)d_in[1];
  const float* bsh  = (const float*)d_in[2];
  const float* Whm  = (const float*)d_in[3];
  const float* bhm  = (const float*)d_in[4];
  const float* Wcls = (const float*)d_in[5];
  const float* bcls = (const float*)d_in[6];
  const float* Wp1  = (const float*)d_in[7];
  const float* bp1  = (const float*)d_in[8];
  const float* Wp2  = (const float*)d_in[9];
  const float* bp2  = (const float*)d_in[10];
  const float* Wq   = (const float*)d_in[11];
  const float* bq   = (const float*)d_in[12];
  const float* Wk   = (const float*)d_in[13];
  const float* bk   = (const float*)d_in[14];
  const float* Wv   = (const float*)d_in[15];
  const float* bv   = (const float*)d_in[16];
  const float* Wo   = (const float*)d_in[17];
  const float* bo   = (const float*)d_in[18];
  const float* g1   = (const float*)d_in[19];
  const float* b1   = (const float*)d_in[20];
  const float* g2   = (const float*)d_in[21];
  const float* b2   = (const float*)d_in[22];
  const float* Wf1  = (const float*)d_in[23];
  const float* bf1  = (const float*)d_in[24];
  const float* Wf2  = (const float*)d_in[25];
  const float* bf2  = (const float*)d_in[26];
  const float* Wc   = (const float*)d_in[27];
  const float* bc   = (const float*)d_in[28];
  const float* Wh   = (const float*)d_in[29];
  const float* bh   = (const float*)d_in[30];
  const float* Wd   = (const float*)d_in[31];
  const float* bd   = (const float*)d_in[32];
  const float* Wr   = (const float*)d_in[33];
  const float* br   = (const float*)d_in[34];
  const float* Whm2 = (const float*)d_in[37];
  const float* bhm2 = (const float*)d_in[38];
  float* out = (float*)d_out;
  float* W = (float*)d_ws;

  const size_t N_LFF  = (size_t)HW*128;
  const size_t OFF_LFF  = 0;
  const size_t OFF_KK   = OFF_LFF + N_LFF;
  const size_t OFF_VV   = OFF_KK + N_LFF;
  const size_t OFF_W6   = OFF_VV + N_LFF;          // 6912
  const size_t OFF_HMS  = OFF_W6 + 6912;           // 152064
  const size_t OFF_VALS = OFF_HMS + 152064;        // 152064
  const size_t OFF_HIST = OFF_VALS + 152064;       // 65536
  const size_t OFF_SCAN = OFF_HIST + 65536;        // 16
  const size_t OFF_CNT  = OFF_SCAN + 16;           // 16
  const size_t OFF_CV   = OFF_CNT + 16;            // CAP
  const size_t OFF_CI   = OFF_CV + CAP;            // CAP
  const size_t OFF_TOPS = OFF_CI + CAP;            // 512
  const size_t OFF_TOPC = OFF_TOPS + 512;          // 512
  const size_t OFF_WQT  = OFF_TOPC + 512;          // 16384
  const size_t OFF_WP2T = OFF_WQT + 16384;         // 16384
  const size_t OFF_WOT  = OFF_WP2T + 16384;        // 16384
  const size_t OFF_WF1T = OFF_WOT + 16384;         // 32768
  const size_t OFF_WF2T = OFF_WF1T + 32768;        // 32768
  const size_t OFF_BQ0  = OFF_WF2T + 32768;        // 184320 floats (= 368640 bf16)
  const size_t OFF_BQ1  = OFF_BQ0 + 184320;
  const size_t OFF_BQ2  = OFF_BQ1 + 184320;
  const size_t TOTAL    = OFF_BQ2 + 184320;
  if (ws_size < TOTAL*sizeof(float)) return;

  ushort_t* BQ0 = (ushort_t*)(W + OFF_BQ0);
  ushort_t* BQ1 = (ushort_t*)(W + OFF_BQ1);
  ushort_t* BQ2 = (ushort_t*)(W + OFF_BQ2);

  // k_wt also zeroes HIST|SCAN|CNT (65568 ints, contiguous at OFF_HIST)
  k_wt    <<<1152, 256, 0, stream>>>(Wsh, Whm, Wq, Wp2, Wo, Wf1, Wf2,
                                     W+OFF_W6,
                                     W+OFF_WQT, W+OFF_WP2T, W+OFF_WOT, W+OFF_WF1T, W+OFF_WF2T,
                                     BQ0, BQ1, BQ2,
                                     (int*)(W+OFF_HIST));
  k_conv1 <<<396, 256, 0, stream>>>(IN, BQ0, BQ1, BQ2, bsh, W+OFF_LFF);
  k_mid   <<<1188, 256, 0, stream>>>(W+OFF_LFF, Wp1, bp1, Wp2, bp2, Wk, bk, Wv, bv,
                                     W+OFF_KK, W+OFF_VV, W+OFF_W6, bhm, W+OFF_HMS);
  k_nms   <<<594,  256, 0, stream>>>(W+OFF_HMS, W+OFF_VALS, (int*)(W+OFF_HIST));
  k_scan  <<<1,   1024, 0, stream>>>((const int*)(W+OFF_HIST), (int*)(W+OFF_SCAN));
  k_collect<<<594, 256, 0, stream>>>(W+OFF_VALS, (const int*)(W+OFF_SCAN),
                                     (int*)(W+OFF_CNT), W+OFF_CV, (int*)(W+OFF_CI));
  k_sort  <<<1,   1024, 0, stream>>>(W+OFF_CV, (const int*)(W+OFF_CI), (const int*)(W+OFF_CNT),
                                     (int*)(W+OFF_TOPS), (int*)(W+OFF_TOPC));
  k_attn  <<<500,  256, 0, stream>>>(W+OFF_KK, W+OFF_VV, W+OFF_LFF,
                                     (const int*)(W+OFF_TOPS), (const int*)(W+OFF_TOPC),
                                     Wcls, bcls, Wp1, bp1, W+OFF_WP2T, bp2, W+OFF_WQT, bq,
                                     W+OFF_WOT, bo, g1, b1, W+OFF_WF1T, bf1, W+OFF_WF2T, bf2, g2, b2,
                                     Wc, bc, Wh, bh, Wd, bd, Wr, br, Whm2, bhm2, out);
}

// Round 13
// 538.921 us; speedup vs baseline: 1.3558x; 1.0078x over previous
//
#include <hip/hip_runtime.h>
#include <math.h>
#include <float.h>

#define XG 192
#define YG 132
#define HW 25344           // 192*132
#define NCLS 6
#define NPROP 500
#define LWIN 441
#define CAP 2048           // candidate cap for top-k sort (one-level select)

typedef unsigned short ushort_t;
typedef __attribute__((ext_vector_type(8))) short bf8v;   // 8 bf16 (4 VGPRs)
typedef __attribute__((ext_vector_type(4))) float f4v;    // 4 fp32 acc

static __device__ __forceinline__ int imin(int a,int b){return a<b?a:b;}
static __device__ __forceinline__ int imax(int a,int b){return a>b?a:b;}

// async global->LDS, 16B per lane; LDS dest is wave-uniform base + lane*16
__device__ __forceinline__ void gl_lds16(const float* gp, float* lp){
  __builtin_amdgcn_global_load_lds(
      (const __attribute__((address_space(1))) unsigned int*)gp,
      (__attribute__((address_space(3))) unsigned int*)lp,
      16, 0, 0);
}
__device__ __forceinline__ void gl_lds16u(const ushort_t* gp, ushort_t* lp){
  __builtin_amdgcn_global_load_lds(
      (const __attribute__((address_space(1))) unsigned int*)gp,
      (__attribute__((address_space(3))) unsigned int*)lp,
      16, 0, 0);
}

__device__ __forceinline__ ushort_t f2bf(float x){          // RNE truncate to bf16
  unsigned u = __float_as_uint(x);
  return (ushort_t)((u + 0x7FFFu + ((u>>16)&1u)) >> 16);
}
__device__ __forceinline__ float bf2f(ushort_t h){
  return __uint_as_float(((unsigned)h)<<16);
}

// ---------------- weight prep: bf16-split conv1 weights + W6 + attn transposes + zeroing ----------
// BQs[(tap*8+chunk)*5120 + n*40 + kl] = split_s( Ws[n][chunk*32+kl][tap] ), kl<32; 32..39 pad unused
__global__ __launch_bounds__(256) void k_wt(const float* __restrict__ Ws,
                                            const float* __restrict__ Whm,
                                            const float* __restrict__ Wq,
                                            const float* __restrict__ Wp2,
                                            const float* __restrict__ Wo,
                                            const float* __restrict__ Wf1,
                                            const float* __restrict__ Wf2,
                                            float* __restrict__ W6,
                                            float* __restrict__ WQT,
                                            float* __restrict__ WP2T,
                                            float* __restrict__ WOT,
                                            float* __restrict__ WF1T,
                                            float* __restrict__ WF2T,
                                            ushort_t* __restrict__ BQ0,
                                            ushort_t* __restrict__ BQ1,
                                            ushort_t* __restrict__ BQ2,
                                            int* __restrict__ Z){
  int t = blockIdx.x*256 + threadIdx.x;
  if (t < 294912){
    int kl = t & 31;
    int rest = t >> 5;
    int n = rest & 127;
    int tc = rest >> 7;            // tap*8 + chunk
    int tap = tc >> 3, chunk = tc & 7;
    int c = chunk*32 + kl;
    float v = Ws[(size_t)n*2304 + c*9 + tap];
    ushort_t h0 = f2bf(v);
    float r1 = v - bf2f(h0);
    ushort_t h1 = f2bf(r1);
    float r2 = r1 - bf2f(h1);
    ushort_t h2 = f2bf(r2);
    size_t dst = (size_t)tc*5120 + n*40 + kl;
    BQ0[dst] = h0; BQ1[dst] = h1; BQ2[dst] = h2;
  }
  if (t < 6912){
    int c = t & 127, row = t >> 7;      // row = cls*9+tap, 54 rows
    int cls = row / 9, tap = row % 9;
    W6[t] = Whm[(size_t)cls*1152 + c*9 + tap];
  }
  if (t < 16384){
    int k = t & 127, c = t >> 7;
    WQT[t]  = Wq [(size_t)k*128 + c];
    WP2T[t] = Wp2[(size_t)k*128 + c];
    WOT[t]  = Wo [(size_t)k*128 + c];
  }
  if (t < 32768){
    { int k = t & 127, o = t >> 7;  WF1T[t] = Wf1[(size_t)k*256 + o]; }
    { int k = t & 255, c = t >> 8;  WF2T[t] = Wf2[(size_t)k*128 + c]; }
  }
  if (t < 65568) Z[t] = 0;              // HIST 65536 | SCAN 16 | CNT 16
}

// ---------------- conv1 v11: split-bf16 MFMA implicit GEMM, K-split x2 ----------------
// grid (396, 2): 396 = 3 i-strips(64) x 132 cols; blockIdx.y = 128-ch half (chunks g*4..g*4+3).
// block 256 = 4 waves. M=64, N=128; per k-step one 16x16x32 MFMA-K, 6 split terms.
// Raw fp32 partials -> P[g]; k_cadd2 combines with bias+relu.
__global__ __launch_bounds__(256, 3) void k_conv1(const float* __restrict__ IN,
                                                  const ushort_t* __restrict__ BQ0,
                                                  const ushort_t* __restrict__ BQ1,
                                                  const ushort_t* __restrict__ BQ2,
                                                  float* __restrict__ P0,
                                                  float* __restrict__ P1){
  const int b  = blockIdx.x;
  const int g  = blockIdx.y;
  const int i0 = (b % 3) * 64;
  const int j  = b / 3;
  const int tid = threadIdx.x;
  const int w    = tid >> 6;
  const int lane = tid & 63;
  const int l15  = lane & 15, quad = lane >> 4;
  __shared__ __align__(16) ushort_t SM[23280];   // A: 3x2640 | B: 3x5120 (46560 B)
  ushort_t* As0 = SM;                 // [px 66][chpad 40]
  ushort_t* As1 = SM + 2640;
  ushort_t* As2 = SM + 5280;
  ushort_t* Bs0 = SM + 7920;          // [n 128][chpad 40]
  ushort_t* Bs1 = SM + 13040;
  ushort_t* Bs2 = SM + 18160;
  f4v acc[4][2];
  #pragma unroll
  for (int mq=0;mq<4;++mq)
    #pragma unroll
    for (int nt=0;nt<2;++nt) acc[mq][nt] = (f4v){0.f,0.f,0.f,0.f};

  for (int cq=0; cq<4; ++cq){
    const int chunk = g*4 + cq;
    for (int kw=0; kw<3; ++kw){
      __syncthreads();                 // prior tap's reads of As/Bs done
      // ---- stage A row (gj = j-1+kw), 32 ch, convert to 3 bf16 splits ----
      {
        int gj = j - 1 + kw;
        bool jok = (unsigned)gj < 132u;
        for (int e = tid; e < 2112; e += 256){
          int c = e / 66, ii = e - c*66;
          int gi = i0 - 1 + ii;
          float v = 0.f;
          if (jok && (unsigned)gi < 192u)
            v = IN[(size_t)(chunk*32 + c)*25344 + gj*192 + gi];
          ushort_t h0 = f2bf(v);
          float r1 = v - bf2f(h0);
          ushort_t h1 = f2bf(r1);
          float r2 = r1 - bf2f(h1);
          ushort_t h2 = f2bf(r2);
          int a = ii*40 + c;
          As0[a] = h0; As1[a] = h1; As2[a] = h2;
        }
      }
      for (int kh=0; kh<3; ++kh){
        if (kh > 0) __syncthreads();   // prior mfma's Bs reads done
        // ---- stage B for tap = kh*3+kw (async, padded rows preserved) ----
        {
          int tc = (kh*3 + kw)*8 + chunk;
          const ushort_t* s0 = BQ0 + (size_t)tc*5120;
          const ushort_t* s1 = BQ1 + (size_t)tc*5120;
          const ushort_t* s2 = BQ2 + (size_t)tc*5120;
          gl_lds16u(s0 + (size_t)tid*8,       Bs0 + (size_t)(w*64)*8);
          gl_lds16u(s0 + (size_t)(256+tid)*8, Bs0 + (size_t)(256 + w*64)*8);
          gl_lds16u(s1 + (size_t)tid*8,       Bs1 + (size_t)(w*64)*8);
          gl_lds16u(s1 + (size_t)(256+tid)*8, Bs1 + (size_t)(256 + w*64)*8);
          gl_lds16u(s2 + (size_t)tid*8,       Bs2 + (size_t)(w*64)*8);
          gl_lds16u(s2 + (size_t)(256+tid)*8, Bs2 + (size_t)(256 + w*64)*8);
          if (tid < 128){
            gl_lds16u(s0 + (size_t)(512+tid)*8, Bs0 + (size_t)(512 + w*64)*8);
            gl_lds16u(s1 + (size_t)(512+tid)*8, Bs1 + (size_t)(512 + w*64)*8);
            gl_lds16u(s2 + (size_t)(512+tid)*8, Bs2 + (size_t)(512 + w*64)*8);
          }
        }
        __syncthreads();               // staging visible (A for kh==0, B always)
        // ---- 6-term split-bf16 MFMA ----
        bf8v A0[4], A1[4], A2[4];
        #pragma unroll
        for (int mq=0; mq<4; ++mq){
          int off = (mq*16 + l15 + kh)*40 + quad*8;
          A0[mq] = *(const bf8v*)&As0[off];
          A1[mq] = *(const bf8v*)&As1[off];
          A2[mq] = *(const bf8v*)&As2[off];
        }
        bf8v B0[2], B1[2], B2[2];
        #pragma unroll
        for (int ntl=0; ntl<2; ++ntl){
          int off = ((w*2+ntl)*16 + l15)*40 + quad*8;
          B0[ntl] = *(const bf8v*)&Bs0[off];
          B1[ntl] = *(const bf8v*)&Bs1[off];
          B2[ntl] = *(const bf8v*)&Bs2[off];
        }
        #pragma unroll
        for (int mq=0;mq<4;++mq){
          #pragma unroll
          for (int ntl=0;ntl<2;++ntl){
            f4v c = acc[mq][ntl];
            c = __builtin_amdgcn_mfma_f32_16x16x32_bf16(A0[mq], B0[ntl], c, 0,0,0);
            c = __builtin_amdgcn_mfma_f32_16x16x32_bf16(A0[mq], B1[ntl], c, 0,0,0);
            c = __builtin_amdgcn_mfma_f32_16x16x32_bf16(A1[mq], B0[ntl], c, 0,0,0);
            c = __builtin_amdgcn_mfma_f32_16x16x32_bf16(A0[mq], B2[ntl], c, 0,0,0);
            c = __builtin_amdgcn_mfma_f32_16x16x32_bf16(A1[mq], B1[ntl], c, 0,0,0);
            c = __builtin_amdgcn_mfma_f32_16x16x32_bf16(A2[mq], B0[ntl], c, 0,0,0);
            acc[mq][ntl] = c;
          }
        }
      }
    }
  }
  // ---- epilogue: LDS transpose -> coalesced raw stores (bias+relu in k_cadd2) ----
  __syncthreads();
  float* Cs = (float*)SM;              // 64 x 128 fp32 = 32768 B <= 46560
  #pragma unroll
  for (int mq=0;mq<4;++mq)
    #pragma unroll
    for (int ntl=0;ntl<2;++ntl)
      #pragma unroll
      for (int r=0;r<4;++r){
        int m = mq*16 + quad*4 + r;          // C/D: row = quad*4+reg
        int oc = (w*2+ntl)*16 + l15;         //      col = lane&15
        Cs[m*128 + oc] = acc[mq][ntl][r];
      }
  __syncthreads();
  float* dst = g ? P1 : P0;
  for (int e = tid; e < 2048; e += 256){
    int m = e >> 5, ocq = e & 31;
    float4 v = *(float4*)&Cs[m*128 + ocq*4];
    int p = (i0 + m)*132 + j;
    *(float4*)&dst[(size_t)p*128 + ocq*4] = v;
  }
}

// ---------------- combine 2 k-split partials + bias + relu ----------------
__global__ __launch_bounds__(256) void k_cadd2(float* __restrict__ LFF,
                                               const float* __restrict__ P0,
                                               const float* __restrict__ P1,
                                               const float* __restrict__ bias){
  int t = blockIdx.x*256 + threadIdx.x;   // 3168*256 = 811008 float4s
  float4 a = ((const float4*)P0)[t];
  float4 b = ((const float4*)P1)[t];
  float4 bs = ((const float4*)bias)[t & 31];
  float4 r;
  r.x = fmaxf(a.x+b.x+bs.x, 0.f);
  r.y = fmaxf(a.y+b.y+bs.y, 0.f);
  r.z = fmaxf(a.z+b.z+bs.z, 0.f);
  r.w = fmaxf(a.w+b.w+bs.w, 0.f);
  ((float4*)LFF)[t] = r;
}

// ---------------- fused (kkvv | conv2) ; both weight paths LDS-staged (R10/R11-proven) ----------
__global__ __launch_bounds__(256) void k_mid(const float* __restrict__ LFF,
                                             const float* __restrict__ W1, const float* __restrict__ b1,
                                             const float* __restrict__ W2, const float* __restrict__ b2,
                                             const float* __restrict__ Wk, const float* __restrict__ bk,
                                             const float* __restrict__ Wv, const float* __restrict__ bv,
                                             float* __restrict__ KK, float* __restrict__ VV,
                                             const float* __restrict__ W6, const float* __restrict__ bhm,
                                             float* __restrict__ HMS){
  __shared__ float smem[12288];   // kkvv: hs 4096 | sf 4096 | wbuf 4096 (48KB)
  const int tid = threadIdx.x;
  const int wv4 = tid >> 6;
  if (blockIdx.x < 792){
    float* hs   = smem;
    float* sf   = smem + 4096;
    float* wbuf = smem + 8192;
    const int p0 = blockIdx.x*32;
    for (int e=tid; e<4096; e+=256){
      int k = e>>5, px = e&31;
      int p = p0+px;
      float bx = (float)(p/132)+0.5f, by = (float)(p%132)+0.5f;
      hs[k*32+px] = fmaxf(bx*W1[k] + by*W1[128+k] + b1[k], 0.f);
    }
    for (int e=tid; e<4096; e+=256){
      int px = e>>7, k = e&127;
      sf[k*32+px] = LFF[(size_t)(p0+px)*128 + k];
    }
    const int pxg = tid & 15, ocg = tid >> 4;   // 16 x 16
    const int px0 = pxg*2, oc0 = ocg*8;
    float accA[2][8];
    #pragma unroll
    for (int r=0;r<2;++r)
      #pragma unroll
      for (int u=0;u<8;++u) accA[r][u]=0.f;
    for (int c0=0; c0<128; c0+=32){
      __syncthreads();
      const float* wsrc = W2 + (size_t)c0*128;
      #pragma unroll
      for (int r=0;r<4;++r)
        gl_lds16(wsrc + (size_t)(r*256+tid)*4, wbuf + (size_t)(r*256+wv4*64)*4);
      __syncthreads();
      #pragma unroll 2
      for (int k=0;k<32;++k){
        float a0 = hs[(c0+k)*32+px0], a1 = hs[(c0+k)*32+px0+1];
        const float4* w = (const float4*)(wbuf + (size_t)k*128 + oc0);
        float4 w0 = w[0], w1 = w[1];
        accA[0][0]+=a0*w0.x; accA[0][1]+=a0*w0.y; accA[0][2]+=a0*w0.z; accA[0][3]+=a0*w0.w;
        accA[0][4]+=a0*w1.x; accA[0][5]+=a0*w1.y; accA[0][6]+=a0*w1.z; accA[0][7]+=a0*w1.w;
        accA[1][0]+=a1*w0.x; accA[1][1]+=a1*w0.y; accA[1][2]+=a1*w0.z; accA[1][3]+=a1*w0.w;
        accA[1][4]+=a1*w1.x; accA[1][5]+=a1*w1.y; accA[1][6]+=a1*w1.z; accA[1][7]+=a1*w1.w;
      }
    }
    __syncthreads();
    #pragma unroll
    for (int u=0;u<8;++u){
      float bb = b2[oc0+u];
      hs[(oc0+u)*32+px0]   = sf[(oc0+u)*32+px0]   + accA[0][u] + bb;
      hs[(oc0+u)*32+px0+1] = sf[(oc0+u)*32+px0+1] + accA[1][u] + bb;
    }
    float accK[2][8], accV[2][8];
    #pragma unroll
    for (int u=0;u<8;++u){
      float k0 = bk[oc0+u], v0 = bv[oc0+u];
      accK[0][u]=k0; accK[1][u]=k0; accV[0][u]=v0; accV[1][u]=v0;
    }
    for (int c0=0; c0<128; c0+=16){
      __syncthreads();
      #pragma unroll
      for (int r=0;r<2;++r){
        gl_lds16(Wk + (size_t)c0*128 + (size_t)(r*256+tid)*4, wbuf + (size_t)(r*256+wv4*64)*4);
        gl_lds16(Wv + (size_t)c0*128 + (size_t)(r*256+tid)*4, wbuf + 2048 + (size_t)(r*256+wv4*64)*4);
      }
      __syncthreads();
      #pragma unroll 2
      for (int k=0;k<16;++k){
        int kk = c0+k;
        float s0 = hs[kk*32+px0], s1 = hs[kk*32+px0+1];
        float f0 = sf[kk*32+px0], f1 = sf[kk*32+px0+1];
        const float4* wkp = (const float4*)(wbuf + (size_t)k*128 + oc0);
        const float4* wvp = (const float4*)(wbuf + 2048 + (size_t)k*128 + oc0);
        float4 k0v = wkp[0], k1v = wkp[1], v0v = wvp[0], v1v = wvp[1];
        accK[0][0]+=s0*k0v.x; accK[0][1]+=s0*k0v.y; accK[0][2]+=s0*k0v.z; accK[0][3]+=s0*k0v.w;
        accK[0][4]+=s0*k1v.x; accK[0][5]+=s0*k1v.y; accK[0][6]+=s0*k1v.z; accK[0][7]+=s0*k1v.w;
        accK[1][0]+=s1*k0v.x; accK[1][1]+=s1*k0v.y; accK[1][2]+=s1*k0v.z; accK[1][3]+=s1*k0v.w;
        accK[1][4]+=s1*k1v.x; accK[1][5]+=s1*k1v.y; accK[1][6]+=s1*k1v.z; accK[1][7]+=s1*k1v.w;
        accV[0][0]+=f0*v0v.x; accV[0][1]+=f0*v0v.y; accV[0][2]+=f0*v0v.z; accV[0][3]+=f0*v0v.w;
        accV[0][4]+=f0*v1v.x; accV[0][5]+=f0*v1v.y; accV[0][6]+=f0*v1v.z; accV[0][7]+=f0*v1v.w;
        accV[1][0]+=f1*v0v.x; accV[1][1]+=f1*v0v.y; accV[1][2]+=f1*v0v.z; accV[1][3]+=f1*v0v.w;
        accV[1][4]+=f1*v1v.x; accV[1][5]+=f1*v1v.y; accV[1][6]+=f1*v1v.z; accV[1][7]+=f1*v1v.w;
      }
    }
    #pragma unroll
    for (int r=0;r<2;++r){
      int p = p0+px0+r;
      float4* oK = (float4*)(KK + (size_t)p*128 + oc0);
      float4* oV = (float4*)(VV + (size_t)p*128 + oc0);
      float4 t0, t1;
      t0.x=accK[r][0]; t0.y=accK[r][1]; t0.z=accK[r][2]; t0.w=accK[r][3];
      t1.x=accK[r][4]; t1.y=accK[r][5]; t1.z=accK[r][6]; t1.w=accK[r][7];
      oK[0]=t0; oK[1]=t1;
      t0.x=accV[r][0]; t0.y=accV[r][1]; t0.z=accV[r][2]; t0.w=accV[r][3];
      t1.x=accV[r][4]; t1.y=accV[r][5]; t1.z=accV[r][6]; t1.w=accV[r][7];
      oV[0]=t0; oV[1]=t1;
    }
  } else {
    float* w6s = smem;          // 6912 floats
    float* red = smem + 8192;
    for (int e=tid; e<6912; e+=256) w6s[e] = W6[e];
    __syncthreads();
    int lane = tid & 63, wave = tid >> 6;
    int p = (blockIdx.x - 792)*64 + lane;        // 396*64 = 25344
    int i = p/132, j = p%132;
    float acc[6] = {0.f,0.f,0.f,0.f,0.f,0.f};
    int cbase = wave*32;
    #pragma unroll
    for (int kh=0; kh<3; ++kh){
      int gi = i+kh-1;
      if ((unsigned)gi >= 192u) continue;
      #pragma unroll
      for (int kw=0; kw<3; ++kw){
        int gj = j+kw-1;
        if ((unsigned)gj >= 132u) continue;
        const float* row = LFF + (size_t)(gi*132+gj)*128 + cbase;
        int tap = kh*3+kw;
        #pragma unroll
        for (int cq=0; cq<8; ++cq){
          float4 v = *(const float4*)(row + cq*4);
          #pragma unroll
          for (int cls=0; cls<6; ++cls){
            float4 wv = *(const float4*)(w6s + (size_t)(cls*9+tap)*128 + cbase + cq*4);
            acc[cls] += v.x*wv.x + v.y*wv.y + v.z*wv.z + v.w*wv.w;
          }
        }
      }
    }
    __syncthreads();
    #pragma unroll
    for (int c=0;c<6;++c) red[(wave*6+c)*64 + lane] = acc[c];
    __syncthreads();
    if (wave==0){
      #pragma unroll
      for (int c=0;c<6;++c){
        float s = red[c*64+lane] + red[(6+c)*64+lane] + red[(12+c)*64+lane] + red[(18+c)*64+lane] + bhm[c];
        HMS[(size_t)c*HW + p] = 1.f/(1.f+expf(-s));
      }
    }
  }
}

// ---------------- NMS + threshold + 16-bit histogram ----------------
__global__ __launch_bounds__(256) void k_nms(const float* __restrict__ HMS,
                                             float* __restrict__ VALS,
                                             int* __restrict__ HIST){
  int t = blockIdx.x*256 + threadIdx.x;   // 594*256 = 152064
  int c = t / HW, p = t % HW;
  int i = p/132, j = p%132;
  float h = HMS[t];
  float v;
  if (c < 3){
    v = 0.f;
    if (i>=1 && i<=190 && j>=1 && j<=130){
      float m = -1e30f;
      #pragma unroll
      for (int di=-1;di<=1;++di)
        #pragma unroll
        for (int dj=-1;dj<=1;++dj)
          m = fmaxf(m, HMS[(size_t)c*HW + (i+di)*132 + (j+dj)]);
      if (h == m) v = h;
    }
  } else v = h;
  if (!(v > 0.01f)) v = 0.f;
  VALS[t] = v;
  if (v > 0.f) atomicAdd(HIST + (__float_as_uint(v)>>16), 1);
}

// ---------------- level-1 scan: parallel suffix scan (R9-proven) ----------------
__global__ __launch_bounds__(1024) void k_scan(const int* __restrict__ HIST, int* __restrict__ SCAN){
  __shared__ int part[1024];
  __shared__ int gsel;
  int t = threadIdx.x;
  int s = 0, base = t*64;
  for (int u=0;u<64;++u) s += HIST[base+u];
  part[t] = s;
  __syncthreads();
  for (int off=1; off<1024; off<<=1){
    int add = (t+off < 1024) ? part[t+off] : 0;
    __syncthreads();
    part[t] += add;
    __syncthreads();
  }
  int total = part[0];
  int mineI = part[t];
  int nextI = (t < 1023) ? part[t+1] : 0;
  if (mineI >= NPROP && nextI < NPROP) gsel = t;
  if (t == 0 && total < NPROP) gsel = -1;
  __syncthreads();
  int g = gsel;
  if (g < 0){
    if (t==0){ SCAN[0] = 0; SCAN[1] = total; }
    return;
  }
  int cumG = (g < 1023) ? part[g+1] : 0;
  if (t < 64){
    int x = HIST[g*64 + t];
    #pragma unroll
    for (int off=1; off<64; off<<=1){
      int y = __shfl_down(x, off);
      x += (t + off < 64) ? y : 0;
    }
    int Snext = __shfl_down(x, 1);
    int incl  = cumG + x;
    int nextc = (t==63) ? cumG : cumG + Snext;
    if (incl >= NPROP && nextc < NPROP){
      SCAN[0] = g*64 + t;
      SCAN[1] = nextc;
    }
  }
}

// ---------------- collect candidates with bin >= bstar ----------------
__global__ __launch_bounds__(256) void k_collect(const float* __restrict__ VALS,
                                                 const int* __restrict__ SCAN,
                                                 int* __restrict__ CNT,
                                                 float* __restrict__ CV, int* __restrict__ CI){
  int t = blockIdx.x*256 + threadIdx.x;   // 594*256 = 152064
  float v = VALS[t];
  int bstar = SCAN[0];
  if (v > 0.f && (int)(__float_as_uint(v)>>16) >= bstar){
    int pos = atomicAdd(CNT, 1);
    if (pos < CAP){ CV[pos] = v; CI[pos] = t; }
  }
}

// ---------------- bitonic sort candidates (2048), take top-500 ----------------
__global__ __launch_bounds__(1024) void k_sort(const float* __restrict__ CV, const int* __restrict__ CI,
                                               const int* __restrict__ CNT,
                                               int* __restrict__ TOPS, int* __restrict__ TOPC){
  __shared__ float sv[CAP];
  __shared__ int   si[CAP];
  int tid = threadIdx.x;
  int M = imin(CNT[0], CAP);
  for (int i=tid; i<CAP; i+=1024){
    if (i < M){ sv[i] = CV[i]; si[i] = CI[i]; }
    else      { sv[i] = -1.f;  si[i] = 0x7fffffff; }
  }
  __syncthreads();
  for (int k=2; k<=CAP; k<<=1){
    for (int j=k>>1; j>0; j>>=1){
      for (int i=tid; i<CAP; i+=1024){
        int p = i ^ j;
        if (p > i){
          bool up = ((i & k) == 0);
          float va = sv[i], vb = sv[p];
          int ia = si[i], ib = si[p];
          bool aFirst = (va > vb) || (va == vb && ia < ib);
          bool bFirst = (vb > va) || (vb == va && ib < ia);
          bool doswap = up ? bFirst : aFirst;
          if (doswap){ sv[i]=vb; sv[p]=va; si[i]=ib; si[p]=ia; }
        }
      }
      __syncthreads();
    }
  }
  for (int t=tid; t<NPROP; t+=1024){
    int idx = imin(si[t], NCLS*HW - 1);
    TOPC[t] = idx / HW;
    TOPS[t] = idx % HW;
  }
}

// ---------------- fused qbuild + attention + LN/FFN/LN + heads + decode (R11-proven) ----------
__global__ __launch_bounds__(256) void k_attn(const float* __restrict__ KK, const float* __restrict__ VV,
                                              const float* __restrict__ LFF,
                                              const int* __restrict__ TOPS, const int* __restrict__ TOPC,
                                              const float* __restrict__ Wcls, const float* __restrict__ bcls,
                                              const float* __restrict__ pW1, const float* __restrict__ pb1,
                                              const float* __restrict__ WP2T, const float* __restrict__ pb2,
                                              const float* __restrict__ WQT, const float* __restrict__ bq,
                                              const float* __restrict__ WOT, const float* __restrict__ bo,
                                              const float* __restrict__ g1, const float* __restrict__ b1,
                                              const float* __restrict__ WF1T, const float* __restrict__ bf1,
                                              const float* __restrict__ WF2T, const float* __restrict__ bf2,
                                              const float* __restrict__ g2, const float* __restrict__ b2,
                                              const float* __restrict__ Wc, const float* __restrict__ bc,
                                              const float* __restrict__ Wh, const float* __restrict__ bh,
                                              const float* __restrict__ Wd, const float* __restrict__ bd,
                                              const float* __restrict__ Wr, const float* __restrict__ br,
                                              const float* __restrict__ Whm2, const float* __restrict__ bhm2,
                                              float* __restrict__ out){
  int n = blockIdx.x, tid = threadIdx.x;
  __shared__ __align__(16) float qhL[128];
  __shared__ float sc[8*441];
  __shared__ int   kiL[441];
  __shared__ __align__(16) float ctxL[128];
  __shared__ float xL[128];
  __shared__ float hidL[256];
  __shared__ float sumsL[8];
  __shared__ float stat[2];
  __shared__ float dots[16];
  int sp = TOPS[n];
  int cls = TOPC[n];
  const int kb64 = (tid>>7)*64, c128 = tid&127;
  float qreg = 0.f;
  if (tid < 128){
    float qx = (float)(sp/132)+0.5f, qy = (float)(sp%132)+0.5f;
    ctxL[tid] = fmaxf(qx*pW1[tid] + qy*pW1[128+tid] + pb1[tid], 0.f);
    qreg = LFF[(size_t)sp*128+tid] + Wcls[tid*6+cls] + bcls[tid];
  }
  __syncthreads();
  {
    const float4* wp = (const float4*)(WP2T + (size_t)c128*128 + kb64);
    float pe = 0.f;
    #pragma unroll
    for (int k4=0;k4<16;++k4){
      float4 w = wp[k4]; int kb = kb64 + k4*4;
      pe += ctxL[kb]*w.x + ctxL[kb+1]*w.y + ctxL[kb+2]*w.z + ctxL[kb+3]*w.w;
    }
    sc[tid] = pe;
  }
  __syncthreads();
  if (tid < 128) xL[tid] = qreg + pb2[tid] + sc[tid] + sc[tid+128];
  __syncthreads();
  {
    const float4* wp = (const float4*)(WQT + (size_t)c128*128 + kb64);
    float qh = 0.f;
    #pragma unroll
    for (int k4=0;k4<16;++k4){
      float4 w = wp[k4]; int kb = kb64 + k4*4;
      qh += xL[kb]*w.x + xL[kb+1]*w.y + xL[kb+2]*w.z + xL[kb+3]*w.w;
    }
    sc[tid] = qh;
  }
  __syncthreads();
  if (tid < 128) qhL[tid] = bq[tid] + sc[tid] + sc[tid+128];
  __syncthreads();
  int spx = sp/192, spy = sp%132;       // faithful to ref's //X_GRID, %Y_GRID
  for (int l = tid; l < 441; l += 256){
    int a = l/21, bb = l%21;
    int kidx = (spx + a - 10)*192 + (spy + bb - 10);
    bool msk = (kidx < 0) || (kidx >= HW);
    int kc = imin(imax(kidx,0), HW-1);
    kiL[l] = kc;
    const float4* kk4 = (const float4*)(KK + (size_t)kc*128);
    const float4* qh4 = (const float4*)qhL;
    #pragma unroll
    for (int hh=0; hh<8; ++hh){
      float acc = 0.f;
      #pragma unroll
      for (int d4=0; d4<4; ++d4){
        float4 kv = kk4[hh*4+d4]; float4 qv = qh4[hh*4+d4];
        acc += kv.x*qv.x + kv.y*qv.y + kv.z*qv.z + kv.w*qv.w;
      }
      sc[hh*441+l] = msk ? -1e9f : acc*0.25f;
    }
  }
  __syncthreads();
  int wave = tid>>6, lane = tid&63;
  for (int hh = wave; hh < 8; hh += 4){
    float mx = -3.0e38f;
    for (int l = lane; l < 441; l += 64) mx = fmaxf(mx, sc[hh*441+l]);
    #pragma unroll
    for (int off=32; off; off>>=1) mx = fmaxf(mx, __shfl_xor(mx, off));
    float sum = 0.f;
    for (int l = lane; l < 441; l += 64){
      float e = __expf(sc[hh*441+l] - mx);
      sc[hh*441+l] = e; sum += e;
    }
    #pragma unroll
    for (int off=32; off; off>>=1) sum += __shfl_xor(sum, off);
    if (lane==0) sumsL[hh] = sum;
  }
  __syncthreads();
  for (int hh = wave; hh < 8; hh += 4){
    float a[16];
    #pragma unroll
    for (int d=0; d<16; ++d) a[d]=0.f;
    for (int l = lane; l < 441; l += 64){
      float w = sc[hh*441+l];
      const float4* vv4 = (const float4*)(VV + (size_t)kiL[l]*128 + hh*16);
      #pragma unroll
      for (int d4=0; d4<4; ++d4){
        float4 v = vv4[d4];
        a[d4*4+0]+=w*v.x; a[d4*4+1]+=w*v.y; a[d4*4+2]+=w*v.z; a[d4*4+3]+=w*v.w;
      }
    }
    #pragma unroll
    for (int d=0; d<16; ++d){
      #pragma unroll
      for (int off=32; off; off>>=1) a[d] += __shfl_xor(a[d], off);
    }
    if (lane==0){
      float inv = 1.f/sumsL[hh];
      #pragma unroll
      for (int d=0; d<16; ++d) ctxL[hh*16+d] = a[d]*inv;
    }
  }
  __syncthreads();
  {
    const float4* wp = (const float4*)(WOT + (size_t)c128*128 + kb64);
    float acc = 0.f;
    #pragma unroll
    for (int k4=0;k4<16;++k4){
      float4 w = wp[k4]; int kb = kb64 + k4*4;
      acc += ctxL[kb]*w.x + ctxL[kb+1]*w.y + ctxL[kb+2]*w.z + ctxL[kb+3]*w.w;
    }
    sc[tid] = acc;
  }
  __syncthreads();
  float x1v = 0.f;
  if (tid < 128){
    x1v = qreg + bo[tid] + sc[tid] + sc[tid+128];
    xL[tid] = x1v;
  }
  __syncthreads();
  if (tid < 64){
    float u0 = xL[tid], u1 = xL[tid+64];
    float s = u0+u1, s2 = u0*u0+u1*u1;
    #pragma unroll
    for (int off=32; off; off>>=1){ s += __shfl_xor(s, off); s2 += __shfl_xor(s2, off); }
    if (tid==0){ float mean = s*(1.f/128.f); float var = s2*(1.f/128.f) - mean*mean;
      stat[0]=mean; stat[1]=rsqrtf(var + 1e-5f); }
  }
  __syncthreads();
  if (tid < 128) xL[tid] = (x1v - stat[0])*stat[1]*g1[tid] + b1[tid];
  __syncthreads();
  {
    const float4* wp = (const float4*)(WF1T + (size_t)tid*128);
    float hv = bf1[tid];
    #pragma unroll 8
    for (int k4=0;k4<32;++k4){
      float4 w = wp[k4]; int kb = k4*4;
      hv += xL[kb]*w.x + xL[kb+1]*w.y + xL[kb+2]*w.z + xL[kb+3]*w.w;
    }
    hidL[tid] = fmaxf(hv, 0.f);
  }
  __syncthreads();
  {
    int kb0 = (tid>>7)*128;
    const float4* wp = (const float4*)(WF2T + (size_t)c128*256 + kb0);
    float acc = 0.f;
    #pragma unroll 8
    for (int k4=0;k4<32;++k4){
      float4 w = wp[k4]; int kb = kb0 + k4*4;
      acc += hidL[kb]*w.x + hidL[kb+1]*w.y + hidL[kb+2]*w.z + hidL[kb+3]*w.w;
    }
    sc[tid] = acc;
  }
  __syncthreads();
  float x2v = 0.f;
  if (tid < 128) x2v = xL[tid] + bf2[tid] + sc[tid] + sc[tid+128];
  __syncthreads();
  if (tid < 128) hidL[tid] = x2v;
  __syncthreads();
  if (tid < 64){
    float u0 = hidL[tid], u1 = hidL[tid+64];
    float s = u0+u1, s2 = u0*u0+u1*u1;
    #pragma unroll
    for (int off=32; off; off>>=1){ s += __shfl_xor(s, off); s2 += __shfl_xor(s2, off); }
    if (tid==0){ float mean = s*(1.f/128.f); float var = s2*(1.f/128.f) - mean*mean;
      stat[0]=mean; stat[1]=rsqrtf(var + 1e-5f); }
  }
  __syncthreads();
  if (tid < 128) xL[tid] = (x2v - stat[0])*stat[1]*g2[tid] + b2[tid];   // final x2
  __syncthreads();
  if (tid < 14){
    const float* Wp; float bb;
    if (tid < 2)      { Wp = Wc + tid*128;        bb = bc[tid];      }
    else if (tid < 3) { Wp = Wh;                  bb = bh[0];        }
    else if (tid < 6) { Wp = Wd + (tid-3)*128;    bb = bd[tid-3];    }
    else if (tid < 8) { Wp = Wr + (tid-6)*128;    bb = br[tid-6];    }
    else              { Wp = Whm2 + (tid-8)*128;  bb = bhm2[tid-8];  }
    float acc = bb;
    for (int k=0;k<128;++k) acc += xL[k]*Wp[k];
    dots[tid] = acc;
  }
  __syncthreads();
  if (tid == 0){
    float qpx = (float)(sp/132)+0.5f, qpy = (float)(sp%132)+0.5f;
    float cx = (dots[0]+qpx)*0.64f - 61.44f;
    float cy = (dots[1]+qpy)*0.64f - 42.24f;
    float e0 = expf(dots[3]), e1 = expf(dots[4]), e2 = expf(dots[5]);
    float hgt = dots[2] - e2*0.5f;
    float rot = atanf(dots[6]/(dots[7] + 1e-6f));
    float bestv = -1.f; int bestc = 0;
    #pragma unroll
    for (int m=0;m<6;++m){
      float s = 1.f/(1.f + expf(-dots[8+m]));
      if (s > bestv){ bestv = s; bestc = m; }
    }
    float* o = out + (size_t)n*9;
    o[0]=cx; o[1]=cy; o[2]=hgt; o[3]=e0; o[4]=e1; o[5]=e2; o[6]=rot;
    o[7]=(float)bestc; o[8]=bestv;
  }
}

// ---------------- launcher ----------------
extern "C" void kernel_launch(void* const* d_in, const int* in_sizes, int n_in,
                              void* d_out, int out_size, void* d_ws, size_t ws_size,
                              hipStream_t stream){
  (void)in_sizes; (void)n_in; (void)out_size;
  const float* IN   = (const float*)d_in[0];
  const float* Wsh  = (const float*)d_in[1];
  const float* bsh  = (const float*)d_in[2];
  const float* Whm  = (const float*)d_in[3];
  const float* bhm  = (const float*)d_in[4];
  const float* Wcls = (const float*)d_in[5];
  const float* bcls = (const float*)d_in[6];
  const float* Wp1  = (const float*)d_in[7];
  const float* bp1  = (const float*)d_in[8];
  const float* Wp2  = (const float*)d_in[9];
  const float* bp2  = (const float*)d_in[10];
  const float* Wq   = (const float*)d_in[11];
  const float* bq   = (const float*)d_in[12];
  const float* Wk   = (const float*)d_in[13];
  const float* bk   = (const float*)d_in[14];
  const float* Wv   = (const float*)d_in[15];
  const float* bv   = (const float*)d_in[16];
  const float* Wo   = (const float*)d_in[17];
  const float* bo   = (const float*)d_in[18];
  const float* g1   = (const float*)d_in[19];
  const float* b1   = (const float*)d_in[20];
  const float* g2   = (const float*)d_in[21];
  const float* b2   = (const float*)d_in[22];
  const float* Wf1  = (const float*)d_in[23];
  const float* bf1  = (const float*)d_in[24];
  const float* Wf2  = (const float*)d_in[25];
  const float* bf2  = (const float*)d_in[26];
  const float* Wc   = (const float*)d_in[27];
  const float* bc   = (const float*)d_in[28];
  const float* Wh   = (const float*)d_in[29];
  const float* bh   = (const float*)d_in[30];
  const float* Wd   = (const float*)d_in[31];
  const float* bd   = (const float*)d_in[32];
  const float* Wr   = (const float*)d_in[33];
  const float* br   = (const float*)d_in[34];
  const float* Whm2 = (const float*)d_in[37];
  const float* bhm2 = (const float*)d_in[38];
  float* out = (float*)d_out;
  float* W = (float*)d_ws;

  const size_t N_LFF  = (size_t)HW*128;
  const size_t OFF_LFF  = 0;
  const size_t OFF_KK   = OFF_LFF + N_LFF;         // conv1 partial P0, then KK
  const size_t OFF_VV   = OFF_KK + N_LFF;          // conv1 partial P1, then VV
  const size_t OFF_W6   = OFF_VV + N_LFF;          // 6912
  const size_t OFF_HMS  = OFF_W6 + 6912;           // 152064
  const size_t OFF_VALS = OFF_HMS + 152064;        // 152064
  const size_t OFF_HIST = OFF_VALS + 152064;       // 65536
  const size_t OFF_SCAN = OFF_HIST + 65536;        // 16
  const size_t OFF_CNT  = OFF_SCAN + 16;           // 16
  const size_t OFF_CV   = OFF_CNT + 16;            // CAP
  const size_t OFF_CI   = OFF_CV + CAP;            // CAP
  const size_t OFF_TOPS = OFF_CI + CAP;            // 512
  const size_t OFF_TOPC = OFF_TOPS + 512;          // 512
  const size_t OFF_WQT  = OFF_TOPC + 512;          // 16384
  const size_t OFF_WP2T = OFF_WQT + 16384;         // 16384
  const size_t OFF_WOT  = OFF_WP2T + 16384;        // 16384
  const size_t OFF_WF1T = OFF_WOT + 16384;         // 32768
  const size_t OFF_WF2T = OFF_WF1T + 32768;        // 32768
  const size_t OFF_BQ0  = OFF_WF2T + 32768;        // 184320 floats (= 368640 bf16)
  const size_t OFF_BQ1  = OFF_BQ0 + 184320;
  const size_t OFF_BQ2  = OFF_BQ1 + 184320;
  const size_t TOTAL    = OFF_BQ2 + 184320;
  if (ws_size < TOTAL*sizeof(float)) return;

  ushort_t* BQ0 = (ushort_t*)(W + OFF_BQ0);
  ushort_t* BQ1 = (ushort_t*)(W + OFF_BQ1);
  ushort_t* BQ2 = (ushort_t*)(W + OFF_BQ2);

  // k_wt also zeroes HIST|SCAN|CNT (65568 ints, contiguous at OFF_HIST)
  k_wt    <<<1152, 256, 0, stream>>>(Wsh, Whm, Wq, Wp2, Wo, Wf1, Wf2,
                                     W+OFF_W6,
                                     W+OFF_WQT, W+OFF_WP2T, W+OFF_WOT, W+OFF_WF1T, W+OFF_WF2T,
                                     BQ0, BQ1, BQ2,
                                     (int*)(W+OFF_HIST));
  k_conv1 <<<dim3(396,2), 256, 0, stream>>>(IN, BQ0, BQ1, BQ2, W+OFF_KK, W+OFF_VV);
  k_cadd2 <<<3168, 256, 0, stream>>>(W+OFF_LFF, W+OFF_KK, W+OFF_VV, bsh);
  k_mid   <<<1188, 256, 0, stream>>>(W+OFF_LFF, Wp1, bp1, Wp2, bp2, Wk, bk, Wv, bv,
                                     W+OFF_KK, W+OFF_VV, W+OFF_W6, bhm, W+OFF_HMS);
  k_nms   <<<594,  256, 0, stream>>>(W+OFF_HMS, W+OFF_VALS, (int*)(W+OFF_HIST));
  k_scan  <<<1,   1024, 0, stream>>>((const int*)(W+OFF_HIST), (int*)(W+OFF_SCAN));
  k_collect<<<594, 256, 0, stream>>>(W+OFF_VALS, (const int*)(W+OFF_SCAN),
                                     (int*)(W+OFF_CNT), W+OFF_CV, (int*)(W+OFF_CI));
  k_sort  <<<1,   1024, 0, stream>>>(W+OFF_CV, (const int*)(W+OFF_CI), (const int*)(W+OFF_CNT),
                                     (int*)(W+OFF_TOPS), (int*)(W+OFF_TOPC));
  k_attn  <<<500,  256, 0, stream>>>(W+OFF_KK, W+OFF_VV, W+OFF_LFF,
                                     (const int*)(W+OFF_TOPS), (const int*)(W+OFF_TOPC),
                                     Wcls, bcls, Wp1, bp1, W+OFF_WP2T, bp2, W+OFF_WQT, bq,
                                     W+OFF_WOT, bo, g1, b1, W+OFF_WF1T, bf1, W+OFF_WF2T, bf2, g2, b2,
                                     Wc, bc, Wh, bh, Wd, bd, Wr, br, Whm2, bhm2, out);
}